// Round 1
// baseline (356.623 us; speedup 1.0000x reference)
//
#include <hip/hip_runtime.h>
#include <math.h>

#define BB 16
#define QQ 500
#define NN 128
#define KK2 34   // 17 keypoints * 2

// ---------------------------------------------------------------------------
// Kernel 1: cost matrix  C[b][q][n]  (fp32, exact op order of the reference)
// Also writes transposed CT[b][n][q] (for coalesced LSA reads) when enabled.
// ---------------------------------------------------------------------------
__global__ __launch_bounds__(128) void cost_kernel(
    const float* __restrict__ pb,   // (B,Q,4) cxcywh
    const float* __restrict__ pk,   // (B,Q,17,2)
    const float* __restrict__ tb,   // (B,N,4)
    const float* __restrict__ tk,   // (B,N,17,2)
    float* __restrict__ C,          // (B,Q,N)
    float* __restrict__ CT,         // (B,N,Q) or nullptr
    int writeCT)
{
#pragma clang fp contract(off)
    const int q = blockIdx.x;
    const int b = blockIdx.y;
    const int n = threadIdx.x;

    __shared__ float spb[4];
    __shared__ float spk[KK2];
    if (threadIdx.x < 4)
        spb[threadIdx.x] = pb[((size_t)b * QQ + q) * 4 + threadIdx.x];
    if (threadIdx.x < KK2)
        spk[threadIdx.x] = pk[((size_t)b * QQ + q) * KK2 + threadIdx.x];
    __syncthreads();

    const float pcx = spb[0], pcy = spb[1], pw = spb[2], ph = spb[3];

    const size_t tbase = ((size_t)b * NN + n) * 4;
    const float tcx = tb[tbase + 0];
    const float tcy = tb[tbase + 1];
    const float tw  = tb[tbase + 2];
    const float th  = tb[tbase + 3];

    // ---- L1 bbox cost (sequential sum, k = 0..3) ----
    float cb = fabsf(pcx - tcx);
    cb = cb + fabsf(pcy - tcy);
    cb = cb + fabsf(pw - tw);
    cb = cb + fabsf(ph - th);

    // ---- GIoU cost ----
    float px0 = pcx - 0.5f * pw;
    float py0 = pcy - 0.5f * ph;
    float px1 = pcx + 0.5f * pw;
    float py1 = pcy + 0.5f * ph;
    px1 = fmaxf(px1, px0 + 1e-4f);
    py1 = fmaxf(py1, py0 + 1e-4f);

    float tx0 = tcx - 0.5f * tw;
    float ty0 = tcy - 0.5f * th;
    float tx1 = tcx + 0.5f * tw;
    float ty1 = tcy + 0.5f * th;
    tx1 = fmaxf(tx1, tx0 + 1e-4f);
    ty1 = fmaxf(ty1, ty0 + 1e-4f);

    const float area_p = (px1 - px0) * (py1 - py0);
    const float area_t = (tx1 - tx0) * (ty1 - ty0);

    const float ltx = fmaxf(px0, tx0);
    const float lty = fmaxf(py0, ty0);
    const float rbx = fminf(px1, tx1);
    const float rby = fminf(py1, ty1);
    const float wx = fmaxf(rbx - ltx, 0.0f);
    const float wy = fmaxf(rby - lty, 0.0f);
    const float inter = wx * wy;
    const float uni = (area_p + area_t) - inter;
    const float iou = inter / uni;

    const float ex0 = fminf(px0, tx0);
    const float ey0 = fminf(py0, ty0);
    const float ex1 = fmaxf(px1, tx1);
    const float ey1 = fmaxf(py1, ty1);
    const float ewx = fmaxf(ex1 - ex0, 0.0f);
    const float ewy = fmaxf(ey1 - ey0, 0.0f);
    const float enc = ewx * ewy;

    const float giou = iou - (enc - uni) / enc;
    const float cg = -giou;

    // ---- keypoint L1 cost (sequential sum, k = 0..33) ----
    const size_t kbase = ((size_t)b * NN + n) * KK2;
    float ck = 0.0f;
    for (int k = 0; k < KK2; ++k)
        ck = ck + fabsf(spk[k] - tk[kbase + k]);

    const float Cv = (5.0f * cb + 2.0f * cg) + ck;

    C[((size_t)b * QQ + q) * NN + n] = Cv;
    if (writeCT)
        CT[((size_t)b * NN + n) * QQ + q] = Cv;
}

// ---------------------------------------------------------------------------
// Kernel 2: per-batch rectangular LSA (JV / shortest augmenting path),
// exact replica of the reference _lsa on cost[b].T (N rows x Q cols),
// including np.argmin first-minimum tie-breaking.
// One block per batch image, 512 threads, column-parallel Dijkstra steps.
// ---------------------------------------------------------------------------
template <bool USE_CT>
__global__ __launch_bounds__(512) void lsa_kernel(
    const float* __restrict__ C,    // (B,Q,N)
    const float* __restrict__ CT,   // (B,N,Q) or nullptr
    float* __restrict__ out_rows,   // (B,N) as float
    float* __restrict__ out_cols)   // (B,N) as float
{
#pragma clang fp contract(off)
    const int b = blockIdx.x;
    const int tid = threadIdx.x;
    const int lane = tid & 63;
    const int wv = tid >> 6;

    __shared__ double v[QQ];
    __shared__ double spc[QQ];
    __shared__ double u[NN];
    __shared__ int path[QQ];
    __shared__ int row4col[QQ];
    __shared__ int col4row[NN];
    __shared__ unsigned char SC[QQ];
    __shared__ unsigned char SR[NN];
    __shared__ double red_val[8];
    __shared__ int red_idx[8];
    __shared__ double s_minval;
    __shared__ int s_i, s_sink;

    for (int j = tid; j < QQ; j += 512) { v[j] = 0.0; row4col[j] = -1; }
    for (int i = tid; i < NN; i += 512) { u[i] = 0.0; col4row[i] = -1; }
    __syncthreads();

    const float* Cb = C + (size_t)b * QQ * NN;
    const float* CTb = USE_CT ? (CT + (size_t)b * NN * QQ) : nullptr;

    for (int cur = 0; cur < NN; ++cur) {
        for (int j = tid; j < QQ; j += 512) { spc[j] = INFINITY; path[j] = -1; SC[j] = 0; }
        for (int i = tid; i < NN; i += 512) SR[i] = 0;
        if (tid == 0) { s_minval = 0.0; s_i = cur; s_sink = -1; }
        __syncthreads();

        // Dijkstra until a free column (sink) is found
        while (true) {
            const int i = s_i;
            const double minv = s_minval;
            if (tid == 0) SR[i] = 1;

            double myval = INFINITY;
            int myj = QQ;
            if (tid < QQ && !SC[tid]) {
                const double c = USE_CT ? (double)CTb[(size_t)i * QQ + tid]
                                        : (double)Cb[(size_t)tid * NN + i];
                // r = min_val + cost[i,j] - u[i] - v[j]  (numpy op order)
                const double r = ((minv + c) - u[i]) - v[tid];
                if (r < spc[tid]) { spc[tid] = r; path[tid] = i; }
                myval = spc[tid];
                myj = tid;
            }
            // lexicographic (value, index) min == np.argmin first-occurrence
            for (int off = 32; off > 0; off >>= 1) {
                const double ov = __shfl_down(myval, off, 64);
                const int oj = __shfl_down(myj, off, 64);
                if (ov < myval || (ov == myval && oj < myj)) { myval = ov; myj = oj; }
            }
            if (lane == 0) { red_val[wv] = myval; red_idx[wv] = myj; }
            __syncthreads();
            if (tid == 0) {
                double bv = red_val[0];
                int bj = red_idx[0];
                for (int w = 1; w < 8; ++w) {
                    if (red_val[w] < bv || (red_val[w] == bv && red_idx[w] < bj)) {
                        bv = red_val[w]; bj = red_idx[w];
                    }
                }
                s_minval = bv;
                SC[bj] = 1;
                const int r4 = row4col[bj];
                if (r4 < 0) s_sink = bj; else s_i = r4;
            }
            __syncthreads();
            if (s_sink >= 0) break;
        }

        // dual updates (use pre-augmentation col4row, matching the reference)
        const double minv = s_minval;
        const int sink = s_sink;
        if (tid < NN) {
            if (tid == cur) {
                u[tid] = u[tid] + minv;
            } else if (SR[tid]) {
                u[tid] = u[tid] + (minv - spc[col4row[tid]]);
            }
        }
        if (tid < QQ && SC[tid]) {
            v[tid] = v[tid] - (minv - spc[tid]);
        }
        __syncthreads();

        // augment along the alternating path (sequential, tid 0)
        if (tid == 0) {
            int j = sink;
            while (true) {
                const int i2 = path[j];
                row4col[j] = i2;
                const int t2 = col4row[i2];
                col4row[i2] = j;
                j = t2;
                if (i2 == cur) break;
            }
        }
        __syncthreads();
    }

    // rows = sorted assigned-query indices; cols = corresponding target index
    // (col4row values are distinct -> rank by counting smaller values)
    if (tid < NN) {
        const int q = col4row[tid];
        int rank = 0;
        for (int n2 = 0; n2 < NN; ++n2) rank += (col4row[n2] < q) ? 1 : 0;
        out_rows[(size_t)b * NN + rank] = (float)q;
        out_cols[(size_t)b * NN + rank] = (float)tid;
    }
}

// ---------------------------------------------------------------------------
extern "C" void kernel_launch(void* const* d_in, const int* in_sizes, int n_in,
                              void* d_out, int out_size, void* d_ws, size_t ws_size,
                              hipStream_t stream) {
    const float* pb = (const float*)d_in[0];  // pred_boxes     (B,Q,4)
    const float* pk = (const float*)d_in[1];  // pred_keypoints (B,Q,17,2)
    const float* tb = (const float*)d_in[2];  // tgt_boxes      (B,N,4)
    const float* tk = (const float*)d_in[3];  // tgt_keypoints  (B,N,17,2)

    float* outC = (float*)d_out;                       // (B,Q,N)
    float* orows = outC + (size_t)BB * QQ * NN;        // (B,N)
    float* ocols = orows + (size_t)BB * NN;            // (B,N)

    const size_t ct_bytes = (size_t)BB * NN * QQ * sizeof(float);
    const bool useCT = (ws_size >= ct_bytes);
    float* CT = useCT ? (float*)d_ws : nullptr;

    dim3 grid(QQ, BB);
    cost_kernel<<<grid, 128, 0, stream>>>(pb, pk, tb, tk, outC, CT, useCT ? 1 : 0);

    if (useCT)
        lsa_kernel<true><<<BB, 512, 0, stream>>>(outC, CT, orows, ocols);
    else
        lsa_kernel<false><<<BB, 512, 0, stream>>>(outC, nullptr, orows, ocols);
}

// Round 2
// 355.953 us; speedup vs baseline: 1.0019x; 1.0019x over previous
//
#include <hip/hip_runtime.h>
#include <math.h>

#define BB 16
#define QQ 500
#define NN 128
#define KK2 34   // 17 keypoints * 2

// ---------------------------------------------------------------------------
// Kernel 1: cost matrix  C[b][q][n]  (fp32, exact op order of the reference)
// Also writes transposed CT[b][n][q] (for coalesced LSA reads) when enabled.
// UNCHANGED from the passing round-1 version (numerics must stay identical).
// ---------------------------------------------------------------------------
__global__ __launch_bounds__(128) void cost_kernel(
    const float* __restrict__ pb,   // (B,Q,4) cxcywh
    const float* __restrict__ pk,   // (B,Q,17,2)
    const float* __restrict__ tb,   // (B,N,4)
    const float* __restrict__ tk,   // (B,N,17,2)
    float* __restrict__ C,          // (B,Q,N)
    float* __restrict__ CT,         // (B,N,Q) or nullptr
    int writeCT)
{
#pragma clang fp contract(off)
    const int q = blockIdx.x;
    const int b = blockIdx.y;
    const int n = threadIdx.x;

    __shared__ float spb[4];
    __shared__ float spk[KK2];
    if (threadIdx.x < 4)
        spb[threadIdx.x] = pb[((size_t)b * QQ + q) * 4 + threadIdx.x];
    if (threadIdx.x < KK2)
        spk[threadIdx.x] = pk[((size_t)b * QQ + q) * KK2 + threadIdx.x];
    __syncthreads();

    const float pcx = spb[0], pcy = spb[1], pw = spb[2], ph = spb[3];

    const size_t tbase = ((size_t)b * NN + n) * 4;
    const float tcx = tb[tbase + 0];
    const float tcy = tb[tbase + 1];
    const float tw  = tb[tbase + 2];
    const float th  = tb[tbase + 3];

    // ---- L1 bbox cost (sequential sum, k = 0..3) ----
    float cb = fabsf(pcx - tcx);
    cb = cb + fabsf(pcy - tcy);
    cb = cb + fabsf(pw - tw);
    cb = cb + fabsf(ph - th);

    // ---- GIoU cost ----
    float px0 = pcx - 0.5f * pw;
    float py0 = pcy - 0.5f * ph;
    float px1 = pcx + 0.5f * pw;
    float py1 = pcy + 0.5f * ph;
    px1 = fmaxf(px1, px0 + 1e-4f);
    py1 = fmaxf(py1, py0 + 1e-4f);

    float tx0 = tcx - 0.5f * tw;
    float ty0 = tcy - 0.5f * th;
    float tx1 = tcx + 0.5f * tw;
    float ty1 = tcy + 0.5f * th;
    tx1 = fmaxf(tx1, tx0 + 1e-4f);
    ty1 = fmaxf(ty1, ty0 + 1e-4f);

    const float area_p = (px1 - px0) * (py1 - py0);
    const float area_t = (tx1 - tx0) * (ty1 - ty0);

    const float ltx = fmaxf(px0, tx0);
    const float lty = fmaxf(py0, ty0);
    const float rbx = fminf(px1, tx1);
    const float rby = fminf(py1, ty1);
    const float wx = fmaxf(rbx - ltx, 0.0f);
    const float wy = fmaxf(rby - lty, 0.0f);
    const float inter = wx * wy;
    const float uni = (area_p + area_t) - inter;
    const float iou = inter / uni;

    const float ex0 = fminf(px0, tx0);
    const float ey0 = fminf(py0, ty0);
    const float ex1 = fmaxf(px1, tx1);
    const float ey1 = fmaxf(py1, ty1);
    const float ewx = fmaxf(ex1 - ex0, 0.0f);
    const float ewy = fmaxf(ey1 - ey0, 0.0f);
    const float enc = ewx * ewy;

    const float giou = iou - (enc - uni) / enc;
    const float cg = -giou;

    // ---- keypoint L1 cost (sequential sum, k = 0..33) ----
    const size_t kbase = ((size_t)b * NN + n) * KK2;
    float ck = 0.0f;
    for (int k = 0; k < KK2; ++k)
        ck = ck + fabsf(spk[k] - tk[kbase + k]);

    const float Cv = (5.0f * cb + 2.0f * cg) + ck;

    C[((size_t)b * QQ + q) * NN + n] = Cv;
    if (writeCT)
        CT[((size_t)b * NN + n) * QQ + q] = Cv;
}

// ---------------------------------------------------------------------------
// order-preserving double -> uint64 key (monotone bijection, no NaNs here)
// ---------------------------------------------------------------------------
__device__ __forceinline__ unsigned long long dkey(double d) {
    long long bits = __double_as_longlong(d);
    return (unsigned long long)(bits ^ ((bits >> 63) | 0x8000000000000000LL));
}

// constant-index select from an 8-array (keeps arrays in registers, rule #20)
#define SEL8(arr, kq, out) do { \
    out = arr[0]; \
    if ((kq)==1) out = arr[1]; if ((kq)==2) out = arr[2]; if ((kq)==3) out = arr[3]; \
    if ((kq)==4) out = arr[4]; if ((kq)==5) out = arr[5]; if ((kq)==6) out = arr[6]; \
    if ((kq)==7) out = arr[7]; } while (0)

#define SCAT8(arr, kq, val) do { \
    if ((kq)==0) arr[0] = (val); if ((kq)==1) arr[1] = (val); \
    if ((kq)==2) arr[2] = (val); if ((kq)==3) arr[3] = (val); \
    if ((kq)==4) arr[4] = (val); if ((kq)==5) arr[5] = (val); \
    if ((kq)==6) arr[6] = (val); if ((kq)==7) arr[7] = (val); } while (0)

// cross-lane gather spc[jj] (per-lane jj; executed by ALL lanes; jj may be -1)
#define GATHER_SPC(dst, jj) do { \
    int _src = ((jj) >> 3) & 63; int _kq = (jj) & 7; \
    double _g0 = __shfl(spc_[0], _src), _g1 = __shfl(spc_[1], _src); \
    double _g2 = __shfl(spc_[2], _src), _g3 = __shfl(spc_[3], _src); \
    double _g4 = __shfl(spc_[4], _src), _g5 = __shfl(spc_[5], _src); \
    double _g6 = __shfl(spc_[6], _src), _g7 = __shfl(spc_[7], _src); \
    double _r = _g0; \
    if (_kq==1) _r=_g1; if (_kq==2) _r=_g2; if (_kq==3) _r=_g3; if (_kq==4) _r=_g4; \
    if (_kq==5) _r=_g5; if (_kq==6) _r=_g6; if (_kq==7) _r=_g7; \
    dst = _r; } while (0)

// ---------------------------------------------------------------------------
// Kernel 2: per-batch rectangular LSA (JV), exact replica of numpy _lsa on
// cost[b].T (N=128 rows x Q=500 cols) incl. np.argmin first-min tie-break.
// ONE WAVE per batch; all state in registers; cross-lane via shuffles only.
// Lane l owns columns j = 8l..8l+7 (lane-major => ballot lowest-lane tie
// resolution == smallest j) and rows l, l+64.
// ---------------------------------------------------------------------------
template <bool USE_CT>
__global__ __launch_bounds__(64) void lsa_wave_kernel(
    const float* __restrict__ C,    // (B,Q,N)
    const float* __restrict__ CT,   // (B,N,Q) or nullptr
    float* __restrict__ out_rows,   // (B,N) as float
    float* __restrict__ out_cols)   // (B,N) as float
{
#pragma clang fp contract(off)
    const int b = blockIdx.x;
    const int lane = threadIdx.x;

    const float* Cb  = C + (size_t)b * QQ * NN;
    const float* CTb = USE_CT ? (CT + (size_t)b * NN * QQ) : nullptr;

    const int j0 = lane * 8;
    const int nval = (QQ - j0 < 0) ? 0 : ((QQ - j0 > 8) ? 8 : (QQ - j0));

    double v_[8], spc_[8];
    int path_[8], r4c_[8];
    double u0 = 0.0, u1 = 0.0;
    int c4r0 = -1, c4r1 = -1;
#pragma unroll
    for (int k = 0; k < 8; ++k) { v_[k] = 0.0; r4c_[k] = -1; }

    for (int cur = 0; cur < NN; ++cur) {
#pragma unroll
        for (int k = 0; k < 8; ++k) { spc_[k] = INFINITY; path_[k] = -1; }
        unsigned int sc = 0;
        int sr0 = 0, sr1 = 0;
        double minv = 0.0;
        int i = cur, sink = -1;

        while (true) {
            // SR[i] = True (numpy: at top of while loop)
            if (i < 64) { if (lane == i) sr0 = 1; }
            else        { if (lane == i - 64) sr1 = 1; }

            // u[i] broadcast (uniform i)
            double ui = (i < 64) ? __shfl(u0, i) : __shfl(u1, i - 64);

            // cost row i, my 8 columns
            float c_[8];
            if (USE_CT) {
                const float4* p = reinterpret_cast<const float4*>(CTb + (size_t)i * QQ + j0);
                if (nval > 0) {
                    float4 a = p[0];
                    c_[0] = a.x; c_[1] = a.y; c_[2] = a.z; c_[3] = a.w;
                } else { c_[0] = c_[1] = c_[2] = c_[3] = 0.0f; }
                if (nval > 4) {
                    float4 a = p[1];
                    c_[4] = a.x; c_[5] = a.y; c_[6] = a.z; c_[7] = a.w;
                } else { c_[4] = c_[5] = c_[6] = c_[7] = 0.0f; }
            } else {
#pragma unroll
                for (int k = 0; k < 8; ++k)
                    c_[k] = (j0 + k < QQ) ? Cb[(size_t)(j0 + k) * NN + i] : 0.0f;
            }

            // relax: r = ((min_val + cost[i,j]) - u[i]) - v[j]   (numpy order)
#pragma unroll
            for (int k = 0; k < 8; ++k) {
                double r = ((minv + (double)c_[k]) - ui) - v_[k];
                bool ok = (k < nval) && !((sc >> k) & 1) && (r < spc_[k]);
                if (ok) { spc_[k] = r; path_[k] = i; }
            }

            // local first-min over my non-SC columns (ascending k => smallest j)
            double lval = INFINITY; int lj = 0x7fffffff;
#pragma unroll
            for (int k = 0; k < 8; ++k) {
                bool okk = (k < nval) && !((sc >> k) & 1);
                if (okk && (spc_[k] < lval)) { lval = spc_[k]; lj = j0 + k; }
            }

            // 6-level butterfly min on order-preserving key; ballot lowest lane
            unsigned long long myk = dkey(lval);
            unsigned long long gk = myk;
#pragma unroll
            for (int off = 1; off < 64; off <<= 1) {
                unsigned long long o = __shfl_xor(gk, off);
                gk = (o < gk) ? o : gk;
            }
            unsigned long long mball = __ballot(myk == gk);
            int winner = __ffsll((unsigned long long)mball) - 1;
            int jmin = __shfl(lj, winner);
            double minv_next = __shfl(lval, winner);

            // SC[jmin] = True
            if (lane == (jmin >> 3)) sc |= 1u << (jmin & 7);

            // r4 = row4col[jmin]  (uniform jmin)
            int kq = jmin & 7;
            int selr; SEL8(r4c_, kq, selr);
            int r4 = __shfl(selr, jmin >> 3);

            minv = minv_next;
            if (r4 < 0) { sink = jmin; break; }
            i = r4;
        }

        // ---- dual updates (pre-augmentation col4row, exact numpy order) ----
        double g0, g1;
        GATHER_SPC(g0, c4r0);
        GATHER_SPC(g1, c4r1);
        if (lane == cur) { u0 = u0 + minv; }
        else if (sr0)    { double t = minv - g0; u0 = u0 + t; }
        if (lane + 64 == cur) { u1 = u1 + minv; }
        else if (sr1)         { double t = minv - g1; u1 = u1 + t; }
#pragma unroll
        for (int k = 0; k < 8; ++k) {
            if ((k < nval) && ((sc >> k) & 1)) {
                double t = minv - spc_[k];
                v_[k] = v_[k] - t;
            }
        }

        // ---- augment along alternating path (uniform j walk) ----
        int j = sink;
        while (true) {
            int kq = j & 7, src = j >> 3;
            int sp; SEL8(path_, kq, sp);
            int i2 = __shfl(sp, src);
            if (lane == src) { SCAT8(r4c_, kq, i2); }   // row4col[j] = i2
            int t2;
            if (i2 < 64) {
                t2 = __shfl(c4r0, i2);
                if (lane == i2) c4r0 = j;
            } else {
                t2 = __shfl(c4r1, i2 - 64);
                if (lane == i2 - 64) c4r1 = j;
            }
            j = t2;
            if (i2 == cur) break;
        }
    }

    // ---- output: rows = sorted assigned-query idx, cols = target idx ----
    __shared__ int s_q[NN];
    s_q[lane] = c4r0;
    s_q[64 + lane] = c4r1;
    __syncthreads();
    int rank0 = 0, rank1 = 0;
    for (int t = 0; t < NN; ++t) {
        int qv = s_q[t];
        rank0 += (qv < c4r0) ? 1 : 0;
        rank1 += (qv < c4r1) ? 1 : 0;
    }
    out_rows[(size_t)b * NN + rank0] = (float)c4r0;
    out_cols[(size_t)b * NN + rank0] = (float)lane;
    out_rows[(size_t)b * NN + rank1] = (float)c4r1;
    out_cols[(size_t)b * NN + rank1] = (float)(64 + lane);
}

// ---------------------------------------------------------------------------
extern "C" void kernel_launch(void* const* d_in, const int* in_sizes, int n_in,
                              void* d_out, int out_size, void* d_ws, size_t ws_size,
                              hipStream_t stream) {
    const float* pb = (const float*)d_in[0];  // pred_boxes     (B,Q,4)
    const float* pk = (const float*)d_in[1];  // pred_keypoints (B,Q,17,2)
    const float* tb = (const float*)d_in[2];  // tgt_boxes      (B,N,4)
    const float* tk = (const float*)d_in[3];  // tgt_keypoints  (B,N,17,2)

    float* outC  = (float*)d_out;                      // (B,Q,N)
    float* orows = outC + (size_t)BB * QQ * NN;        // (B,N)
    float* ocols = orows + (size_t)BB * NN;            // (B,N)

    const size_t ct_bytes = (size_t)BB * NN * QQ * sizeof(float);
    const bool useCT = (ws_size >= ct_bytes);
    float* CT = useCT ? (float*)d_ws : nullptr;

    dim3 grid(QQ, BB);
    cost_kernel<<<grid, 128, 0, stream>>>(pb, pk, tb, tk, outC, CT, useCT ? 1 : 0);

    if (useCT)
        lsa_wave_kernel<true><<<BB, 64, 0, stream>>>(outC, CT, orows, ocols);
    else
        lsa_wave_kernel<false><<<BB, 64, 0, stream>>>(outC, nullptr, orows, ocols);
}

// Round 3
// 301.130 us; speedup vs baseline: 1.1843x; 1.1821x over previous
//
#include <hip/hip_runtime.h>
#include <math.h>

#define BB 16
#define QQ 500
#define NN 128
#define KK2 34   // 17 keypoints * 2

// ---------------------------------------------------------------------------
// Kernel 1: cost matrix  C[b][q][n]  (fp32, exact op order of the reference)
// Also writes transposed CT[b][n][q] (for coalesced LSA reads) when enabled.
// UNCHANGED from the passing round-1 version (numerics must stay identical).
// ---------------------------------------------------------------------------
__global__ __launch_bounds__(128) void cost_kernel(
    const float* __restrict__ pb,   // (B,Q,4) cxcywh
    const float* __restrict__ pk,   // (B,Q,17,2)
    const float* __restrict__ tb,   // (B,N,4)
    const float* __restrict__ tk,   // (B,N,17,2)
    float* __restrict__ C,          // (B,Q,N)
    float* __restrict__ CT,         // (B,N,Q) or nullptr
    int writeCT)
{
#pragma clang fp contract(off)
    const int q = blockIdx.x;
    const int b = blockIdx.y;
    const int n = threadIdx.x;

    __shared__ float spb[4];
    __shared__ float spk[KK2];
    if (threadIdx.x < 4)
        spb[threadIdx.x] = pb[((size_t)b * QQ + q) * 4 + threadIdx.x];
    if (threadIdx.x < KK2)
        spk[threadIdx.x] = pk[((size_t)b * QQ + q) * KK2 + threadIdx.x];
    __syncthreads();

    const float pcx = spb[0], pcy = spb[1], pw = spb[2], ph = spb[3];

    const size_t tbase = ((size_t)b * NN + n) * 4;
    const float tcx = tb[tbase + 0];
    const float tcy = tb[tbase + 1];
    const float tw  = tb[tbase + 2];
    const float th  = tb[tbase + 3];

    // ---- L1 bbox cost (sequential sum, k = 0..3) ----
    float cb = fabsf(pcx - tcx);
    cb = cb + fabsf(pcy - tcy);
    cb = cb + fabsf(pw - tw);
    cb = cb + fabsf(ph - th);

    // ---- GIoU cost ----
    float px0 = pcx - 0.5f * pw;
    float py0 = pcy - 0.5f * ph;
    float px1 = pcx + 0.5f * pw;
    float py1 = pcy + 0.5f * ph;
    px1 = fmaxf(px1, px0 + 1e-4f);
    py1 = fmaxf(py1, py0 + 1e-4f);

    float tx0 = tcx - 0.5f * tw;
    float ty0 = tcy - 0.5f * th;
    float tx1 = tcx + 0.5f * tw;
    float ty1 = tcy + 0.5f * th;
    tx1 = fmaxf(tx1, tx0 + 1e-4f);
    ty1 = fmaxf(ty1, ty0 + 1e-4f);

    const float area_p = (px1 - px0) * (py1 - py0);
    const float area_t = (tx1 - tx0) * (ty1 - ty0);

    const float ltx = fmaxf(px0, tx0);
    const float lty = fmaxf(py0, ty0);
    const float rbx = fminf(px1, tx1);
    const float rby = fminf(py1, ty1);
    const float wx = fmaxf(rbx - ltx, 0.0f);
    const float wy = fmaxf(rby - lty, 0.0f);
    const float inter = wx * wy;
    const float uni = (area_p + area_t) - inter;
    const float iou = inter / uni;

    const float ex0 = fminf(px0, tx0);
    const float ey0 = fminf(py0, ty0);
    const float ex1 = fmaxf(px1, tx1);
    const float ey1 = fmaxf(py1, ty1);
    const float ewx = fmaxf(ex1 - ex0, 0.0f);
    const float ewy = fmaxf(ey1 - ey0, 0.0f);
    const float enc = ewx * ewy;

    const float giou = iou - (enc - uni) / enc;
    const float cg = -giou;

    // ---- keypoint L1 cost (sequential sum, k = 0..33) ----
    const size_t kbase = ((size_t)b * NN + n) * KK2;
    float ck = 0.0f;
    for (int k = 0; k < KK2; ++k)
        ck = ck + fabsf(spk[k] - tk[kbase + k]);

    const float Cv = (5.0f * cb + 2.0f * cg) + ck;

    C[((size_t)b * QQ + q) * NN + n] = Cv;
    if (writeCT)
        CT[((size_t)b * NN + n) * QQ + q] = Cv;
}

// ---------------------------------------------------------------------------
// order-preserving double -> uint64 key (monotone bijection, no NaNs here)
// ---------------------------------------------------------------------------
__device__ __forceinline__ unsigned long long dkey(double d) {
    long long bits = __double_as_longlong(d);
    return (unsigned long long)(bits ^ ((bits >> 63) | 0x8000000000000000LL));
}
__device__ __forceinline__ double dkey_inv(unsigned long long k) {
    long long bits = (k & 0x8000000000000000ULL)
                   ? (long long)(k ^ 0x8000000000000000ULL)
                   : (long long)(~k);
    return __longlong_as_double(bits);
}

// uniform-lane readlane helpers (v_readlane_b32 — scalar pipe, no LDS)
__device__ __forceinline__ int rl_i(int v, int l) {
    return __builtin_amdgcn_readlane(v, l);
}
__device__ __forceinline__ double rl_d(double v, int l) {
    int lo = __builtin_amdgcn_readlane(__double2loint(v), l);
    int hi = __builtin_amdgcn_readlane(__double2hiint(v), l);
    return __hiloint2double(hi, lo);
}

// 64-bit DPP permute of both halves (same ctrl), invalid lanes keep self
template <int CTRL>
__device__ __forceinline__ unsigned long long dpp_u64(unsigned long long x) {
    int lo = (int)(unsigned)(x & 0xffffffffULL);
    int hi = (int)(unsigned)(x >> 32);
    int nlo = __builtin_amdgcn_update_dpp(lo, lo, CTRL, 0xF, 0xF, false);
    int nhi = __builtin_amdgcn_update_dpp(hi, hi, CTRL, 0xF, 0xF, false);
    return ((unsigned long long)(unsigned)nhi << 32) | (unsigned)nlo;
}
#define ROW_SHR1  0x111
#define ROW_SHR2  0x112
#define ROW_SHR4  0x114
#define ROW_SHR8  0x118
#define ROW_BC15  0x142
#define ROW_BC31  0x143

// constant-index select from an 8-array (keeps arrays in registers, rule #20)
#define SEL8(arr, kq, out) do { \
    out = arr[0]; \
    if ((kq)==1) out = arr[1]; if ((kq)==2) out = arr[2]; if ((kq)==3) out = arr[3]; \
    if ((kq)==4) out = arr[4]; if ((kq)==5) out = arr[5]; if ((kq)==6) out = arr[6]; \
    if ((kq)==7) out = arr[7]; } while (0)

#define SCAT8(arr, kq, val) do { \
    if ((kq)==0) arr[0] = (val); if ((kq)==1) arr[1] = (val); \
    if ((kq)==2) arr[2] = (val); if ((kq)==3) arr[3] = (val); \
    if ((kq)==4) arr[4] = (val); if ((kq)==5) arr[5] = (val); \
    if ((kq)==6) arr[6] = (val); if ((kq)==7) arr[7] = (val); } while (0)

// cross-lane gather spc[jj] (per-lane jj; executed by ALL lanes; jj may be -1)
// per-lane source index -> must stay ds_bpermute (__shfl); once/augmentation.
#define GATHER_SPC(dst, jj) do { \
    int _src = ((jj) >> 3) & 63; int _kq = (jj) & 7; \
    double _g0 = __shfl(spc_[0], _src), _g1 = __shfl(spc_[1], _src); \
    double _g2 = __shfl(spc_[2], _src), _g3 = __shfl(spc_[3], _src); \
    double _g4 = __shfl(spc_[4], _src), _g5 = __shfl(spc_[5], _src); \
    double _g6 = __shfl(spc_[6], _src), _g7 = __shfl(spc_[7], _src); \
    double _r = _g0; \
    if (_kq==1) _r=_g1; if (_kq==2) _r=_g2; if (_kq==3) _r=_g3; if (_kq==4) _r=_g4; \
    if (_kq==5) _r=_g5; if (_kq==6) _r=_g6; if (_kq==7) _r=_g7; \
    dst = _r; } while (0)

// ---------------------------------------------------------------------------
// Kernel 2: per-batch rectangular LSA (JV), exact replica of numpy _lsa on
// cost[b].T (N=128 rows x Q=500 cols) incl. np.argmin first-min tie-break.
// ONE WAVE per batch; state in registers; cross-lane via DPP + readlane
// (VALU/scalar pipes) — no LDS on the per-iteration critical path.
// Lane l owns columns j = 8l..8l+7 and rows l, l+64.
// ---------------------------------------------------------------------------
template <bool USE_CT>
__global__ __launch_bounds__(64) void lsa_wave_kernel(
    const float* __restrict__ C,    // (B,Q,N)
    const float* __restrict__ CT,   // (B,N,Q) or nullptr
    float* __restrict__ out_rows,   // (B,N) as float
    float* __restrict__ out_cols)   // (B,N) as float
{
#pragma clang fp contract(off)
    const int b = blockIdx.x;
    const int lane = threadIdx.x;

    const float* Cb  = C + (size_t)b * QQ * NN;
    const float* CTb = USE_CT ? (CT + (size_t)b * NN * QQ) : nullptr;

    const int j0 = lane * 8;
    const int nval = (QQ - j0 < 0) ? 0 : ((QQ - j0 > 8) ? 8 : (QQ - j0));

    double v_[8], spc_[8];
    int path_[8], r4c_[8];
    double u0 = 0.0, u1 = 0.0;
    int c4r0 = -1, c4r1 = -1;
#pragma unroll
    for (int k = 0; k < 8; ++k) { v_[k] = 0.0; r4c_[k] = -1; }

    for (int cur = 0; cur < NN; ++cur) {
#pragma unroll
        for (int k = 0; k < 8; ++k) { spc_[k] = INFINITY; path_[k] = -1; }
        unsigned int sc = 0;
        int sr0 = 0, sr1 = 0;
        double minv = 0.0;
        int i = cur, sink = -1;

        while (true) {
            // cost row i, my 8 columns — issue the load first (L2 latency)
            float c_[8];
            if (USE_CT) {
                const float4* p = reinterpret_cast<const float4*>(CTb + (size_t)i * QQ + j0);
                if (nval > 0) {
                    float4 a = p[0];
                    c_[0] = a.x; c_[1] = a.y; c_[2] = a.z; c_[3] = a.w;
                } else { c_[0] = c_[1] = c_[2] = c_[3] = 0.0f; }
                if (nval > 4) {
                    float4 a = p[1];
                    c_[4] = a.x; c_[5] = a.y; c_[6] = a.z; c_[7] = a.w;
                } else { c_[4] = c_[5] = c_[6] = c_[7] = 0.0f; }
            } else {
#pragma unroll
                for (int k = 0; k < 8; ++k)
                    c_[k] = (j0 + k < QQ) ? Cb[(size_t)(j0 + k) * NN + i] : 0.0f;
            }

            // SR[i] = True
            if (i < 64) { if (lane == i) sr0 = 1; }
            else        { if (lane == i - 64) sr1 = 1; }

            // u[i] broadcast — uniform i => readlane (no LDS)
            double ui = (i < 64) ? rl_d(u0, i) : rl_d(u1, i - 64);

            // relax: r = ((min_val + cost[i,j]) - u[i]) - v[j]   (numpy order)
#pragma unroll
            for (int k = 0; k < 8; ++k) {
                double r = ((minv + (double)c_[k]) - ui) - v_[k];
                bool ok = (k < nval) && !((sc >> k) & 1) && (r < spc_[k]);
                if (ok) { spc_[k] = r; path_[k] = i; }
            }

            // local first-min over my non-SC columns (ascending k => smallest j)
            double lval = INFINITY; int lj = 0x7fffffff;
#pragma unroll
            for (int k = 0; k < 8; ++k) {
                bool okk = (k < nval) && !((sc >> k) & 1);
                if (okk && (spc_[k] < lval)) { lval = spc_[k]; lj = j0 + k; }
            }

            // wave min via DPP prefix-min (VALU pipe, no ds_bpermute)
            unsigned long long myk = dkey(lval);
            unsigned long long k64 = myk, o64;
            o64 = dpp_u64<ROW_SHR1>(k64); if (o64 < k64) k64 = o64;
            o64 = dpp_u64<ROW_SHR2>(k64); if (o64 < k64) k64 = o64;
            o64 = dpp_u64<ROW_SHR4>(k64); if (o64 < k64) k64 = o64;
            o64 = dpp_u64<ROW_SHR8>(k64); if (o64 < k64) k64 = o64;
            o64 = dpp_u64<ROW_BC15>(k64); if (o64 < k64) k64 = o64;
            o64 = dpp_u64<ROW_BC31>(k64); if (o64 < k64) k64 = o64;
            // lane 63 now holds the global min key; broadcast via readlane
            unsigned long long gmin =
                ((unsigned long long)(unsigned)rl_i((int)(unsigned)(k64 >> 32), 63) << 32) |
                (unsigned)rl_i((int)(unsigned)(k64 & 0xffffffffULL), 63);

            // first-occurrence tie-break: lowest lane whose key equals gmin
            unsigned long long mball = __ballot(myk == gmin);
            int winner = __ffsll((long long)mball) - 1;
            int jmin = rl_i(lj, winner);
            double minv_next = dkey_inv(gmin);   // no shuffle needed

            // SC[jmin] = True
            if (lane == (jmin >> 3)) sc |= 1u << (jmin & 7);

            // r4 = row4col[jmin]  (uniform jmin => readlane)
            int kq = jmin & 7;
            int selr; SEL8(r4c_, kq, selr);
            int r4 = rl_i(selr, jmin >> 3);

            minv = minv_next;
            if (r4 < 0) { sink = jmin; break; }
            i = r4;
        }

        // ---- dual updates (pre-augmentation col4row, exact numpy order) ----
        double g0, g1;
        GATHER_SPC(g0, c4r0);
        GATHER_SPC(g1, c4r1);
        if (lane == cur) { u0 = u0 + minv; }
        else if (sr0)    { double t = minv - g0; u0 = u0 + t; }
        if (lane + 64 == cur) { u1 = u1 + minv; }
        else if (sr1)         { double t = minv - g1; u1 = u1 + t; }
#pragma unroll
        for (int k = 0; k < 8; ++k) {
            if ((k < nval) && ((sc >> k) & 1)) {
                double t = minv - spc_[k];
                v_[k] = v_[k] - t;
            }
        }

        // ---- augment along alternating path (uniform j walk, readlane) ----
        int j = sink;
        while (true) {
            int kq = j & 7, src = j >> 3;
            int sp; SEL8(path_, kq, sp);
            int i2 = rl_i(sp, src);
            if (lane == src) { SCAT8(r4c_, kq, i2); }   // row4col[j] = i2
            int t2;
            if (i2 < 64) {
                t2 = rl_i(c4r0, i2);
                if (lane == i2) c4r0 = j;
            } else {
                t2 = rl_i(c4r1, i2 - 64);
                if (lane == i2 - 64) c4r1 = j;
            }
            j = t2;
            if (i2 == cur) break;
        }
    }

    // ---- output: rows = sorted assigned-query idx, cols = target idx ----
    __shared__ int s_q[NN];
    s_q[lane] = c4r0;
    s_q[64 + lane] = c4r1;
    __syncthreads();
    int rank0 = 0, rank1 = 0;
    for (int t = 0; t < NN; ++t) {
        int qv = s_q[t];
        rank0 += (qv < c4r0) ? 1 : 0;
        rank1 += (qv < c4r1) ? 1 : 0;
    }
    out_rows[(size_t)b * NN + rank0] = (float)c4r0;
    out_cols[(size_t)b * NN + rank0] = (float)lane;
    out_rows[(size_t)b * NN + rank1] = (float)c4r1;
    out_cols[(size_t)b * NN + rank1] = (float)(64 + lane);
}

// ---------------------------------------------------------------------------
extern "C" void kernel_launch(void* const* d_in, const int* in_sizes, int n_in,
                              void* d_out, int out_size, void* d_ws, size_t ws_size,
                              hipStream_t stream) {
    const float* pb = (const float*)d_in[0];  // pred_boxes     (B,Q,4)
    const float* pk = (const float*)d_in[1];  // pred_keypoints (B,Q,17,2)
    const float* tb = (const float*)d_in[2];  // tgt_boxes      (B,N,4)
    const float* tk = (const float*)d_in[3];  // tgt_keypoints  (B,N,17,2)

    float* outC  = (float*)d_out;                      // (B,Q,N)
    float* orows = outC + (size_t)BB * QQ * NN;        // (B,N)
    float* ocols = orows + (size_t)BB * NN;            // (B,N)

    const size_t ct_bytes = (size_t)BB * NN * QQ * sizeof(float);
    const bool useCT = (ws_size >= ct_bytes);
    float* CT = useCT ? (float*)d_ws : nullptr;

    dim3 grid(QQ, BB);
    cost_kernel<<<grid, 128, 0, stream>>>(pb, pk, tb, tk, outC, CT, useCT ? 1 : 0);

    if (useCT)
        lsa_wave_kernel<true><<<BB, 64, 0, stream>>>(outC, CT, orows, ocols);
    else
        lsa_wave_kernel<false><<<BB, 64, 0, stream>>>(outC, nullptr, orows, ocols);
}

// Round 4
// 298.026 us; speedup vs baseline: 1.1966x; 1.0104x over previous
//
#include <hip/hip_runtime.h>
#include <math.h>

#define BB 16
#define QQ 500
#define NN 128
#define KK2 34   // 17 keypoints * 2

// dynamic LDS layout (bytes)
#define ROW_STRIDE 2048               // 512 floats per cached row
#define ROWS_BYTES (64 * ROW_STRIDE)  // rows 0..63 cached: 131072
#define SPC_OFF    ROWS_BYTES
#define SPC_LANE_STRIDE 80            // 8 doubles + 16B pad (16B-aligned)
#define SPC_BYTES  (64 * SPC_LANE_STRIDE)
#define SQ_OFF     (SPC_OFF + SPC_BYTES)
#define SMEM_BYTES (SQ_OFF + NN * 4)  // 136704

// ---------------------------------------------------------------------------
// Kernel 1: cost matrix  C[b][q][n]  (fp32, exact op order of the reference)
// Also writes transposed CT[b][n][q]. UNCHANGED (numerics must stay identical).
// ---------------------------------------------------------------------------
__global__ __launch_bounds__(128) void cost_kernel(
    const float* __restrict__ pb,   // (B,Q,4) cxcywh
    const float* __restrict__ pk,   // (B,Q,17,2)
    const float* __restrict__ tb,   // (B,N,4)
    const float* __restrict__ tk,   // (B,N,17,2)
    float* __restrict__ C,          // (B,Q,N)
    float* __restrict__ CT,         // (B,N,Q) or nullptr
    int writeCT)
{
#pragma clang fp contract(off)
    const int q = blockIdx.x;
    const int b = blockIdx.y;
    const int n = threadIdx.x;

    __shared__ float spb[4];
    __shared__ float spk[KK2];
    if (threadIdx.x < 4)
        spb[threadIdx.x] = pb[((size_t)b * QQ + q) * 4 + threadIdx.x];
    if (threadIdx.x < KK2)
        spk[threadIdx.x] = pk[((size_t)b * QQ + q) * KK2 + threadIdx.x];
    __syncthreads();

    const float pcx = spb[0], pcy = spb[1], pw = spb[2], ph = spb[3];

    const size_t tbase = ((size_t)b * NN + n) * 4;
    const float tcx = tb[tbase + 0];
    const float tcy = tb[tbase + 1];
    const float tw  = tb[tbase + 2];
    const float th  = tb[tbase + 3];

    float cb = fabsf(pcx - tcx);
    cb = cb + fabsf(pcy - tcy);
    cb = cb + fabsf(pw - tw);
    cb = cb + fabsf(ph - th);

    float px0 = pcx - 0.5f * pw;
    float py0 = pcy - 0.5f * ph;
    float px1 = pcx + 0.5f * pw;
    float py1 = pcy + 0.5f * ph;
    px1 = fmaxf(px1, px0 + 1e-4f);
    py1 = fmaxf(py1, py0 + 1e-4f);

    float tx0 = tcx - 0.5f * tw;
    float ty0 = tcy - 0.5f * th;
    float tx1 = tcx + 0.5f * tw;
    float ty1 = tcy + 0.5f * th;
    tx1 = fmaxf(tx1, tx0 + 1e-4f);
    ty1 = fmaxf(ty1, ty0 + 1e-4f);

    const float area_p = (px1 - px0) * (py1 - py0);
    const float area_t = (tx1 - tx0) * (ty1 - ty0);

    const float ltx = fmaxf(px0, tx0);
    const float lty = fmaxf(py0, ty0);
    const float rbx = fminf(px1, tx1);
    const float rby = fminf(py1, ty1);
    const float wx = fmaxf(rbx - ltx, 0.0f);
    const float wy = fmaxf(rby - lty, 0.0f);
    const float inter = wx * wy;
    const float uni = (area_p + area_t) - inter;
    const float iou = inter / uni;

    const float ex0 = fminf(px0, tx0);
    const float ey0 = fminf(py0, ty0);
    const float ex1 = fmaxf(px1, tx1);
    const float ey1 = fmaxf(py1, ty1);
    const float ewx = fmaxf(ex1 - ex0, 0.0f);
    const float ewy = fmaxf(ey1 - ey0, 0.0f);
    const float enc = ewx * ewy;

    const float giou = iou - (enc - uni) / enc;
    const float cg = -giou;

    const size_t kbase = ((size_t)b * NN + n) * KK2;
    float ck = 0.0f;
    for (int k = 0; k < KK2; ++k)
        ck = ck + fabsf(spk[k] - tk[kbase + k]);

    const float Cv = (5.0f * cb + 2.0f * cg) + ck;

    C[((size_t)b * QQ + q) * NN + n] = Cv;
    if (writeCT)
        CT[((size_t)b * NN + n) * QQ + q] = Cv;
}

// uniform-lane readlane helpers (scalar pipe, no LDS)
__device__ __forceinline__ int rl_i(int v, int l) {
    return __builtin_amdgcn_readlane(v, l);
}
__device__ __forceinline__ double rl_d(double v, int l) {
    int lo = __builtin_amdgcn_readlane(__double2loint(v), l);
    int hi = __builtin_amdgcn_readlane(__double2hiint(v), l);
    return __hiloint2double(hi, lo);
}

// one DPP min step on f64 (two 32-bit dpp movs + v_min_f64)
template <int CTRL>
__device__ __forceinline__ double dpp_fmin_step(double x) {
    int lo = __double2loint(x);
    int hi = __double2hiint(x);
    int nlo = __builtin_amdgcn_update_dpp(lo, lo, CTRL, 0xF, 0xF, false);
    int nhi = __builtin_amdgcn_update_dpp(hi, hi, CTRL, 0xF, 0xF, false);
    return fmin(__hiloint2double(nhi, nlo), x);
}
#define ROW_SHR1  0x111
#define ROW_SHR2  0x112
#define ROW_SHR4  0x114
#define ROW_SHR8  0x118
#define ROW_BC15  0x142
#define ROW_BC31  0x143

// constant-index select/scatter on 8-arrays (register-resident, rule #20)
#define SEL8(arr, kq, out) do { \
    out = arr[0]; \
    if ((kq)==1) out = arr[1]; if ((kq)==2) out = arr[2]; if ((kq)==3) out = arr[3]; \
    if ((kq)==4) out = arr[4]; if ((kq)==5) out = arr[5]; if ((kq)==6) out = arr[6]; \
    if ((kq)==7) out = arr[7]; } while (0)

#define SCAT8(arr, kq, val) do { \
    if ((kq)==0) arr[0] = (val); if ((kq)==1) arr[1] = (val); \
    if ((kq)==2) arr[2] = (val); if ((kq)==3) arr[3] = (val); \
    if ((kq)==4) arr[4] = (val); if ((kq)==5) arr[5] = (val); \
    if ((kq)==6) arr[6] = (val); if ((kq)==7) arr[7] = (val); } while (0)

// spc LDS address for column j (16B-aligned lane blocks, padded stride)
__device__ __forceinline__ int spc_addr(int j) {
    return SPC_OFF + (j >> 3) * SPC_LANE_STRIDE + (j & 7) * 8;
}

// ---------------------------------------------------------------------------
// Kernel 2: per-batch rectangular LSA (JV), exact replica of numpy _lsa on
// cost[b].T (N=128 rows x Q=500 cols) incl. np.argmin first-min tie-break.
// ONE WAVE per batch. Rows 0..63 of the cost slice cached in LDS; rows
// 64..127 self-warmed into the local XCD L2. Cross-lane via DPP + readlane.
// Lane l owns columns j = 8l..8l+7 and rows l, l+64.
// ---------------------------------------------------------------------------
template <bool USE_CT>
__global__ __launch_bounds__(64) void lsa_wave_kernel(
    const float* __restrict__ C,    // (B,Q,N)
    const float* __restrict__ CT,   // (B,N,Q) or nullptr
    float* __restrict__ out_rows,   // (B,N) as float
    float* __restrict__ out_cols)   // (B,N) as float
{
#pragma clang fp contract(off)
    extern __shared__ char smem[];
    const int b = blockIdx.x;
    const int lane = threadIdx.x;

    const float* Cb  = C + (size_t)b * QQ * NN;
    const float* CTb = USE_CT ? (CT + (size_t)b * NN * QQ) : nullptr;

    const int j0 = lane * 8;
    const int nval = (QQ - j0 < 0) ? 0 : ((QQ - j0 > 8) ? 8 : (QQ - j0));

    // ---- zero the LDS row pads (cols 500..511, rows 0..63) ----
    for (int x = lane; x < 64 * 12; x += 64) {
        int r = x / 12, c = x % 12;
        *(float*)(smem + r * ROW_STRIDE + (500 + c) * 4) = 0.0f;
    }

    // ---- copy rows 0..63 of this batch's cost slice into LDS ----
    for (int r = 0; r < 64; ++r) {
        if (nval > 0) {
            float4 a;
            if (USE_CT) {
                a = *reinterpret_cast<const float4*>(CTb + (size_t)r * QQ + j0);
            } else {
                a.x = Cb[(size_t)(j0 + 0) * NN + r];
                a.y = Cb[(size_t)(j0 + 1) * NN + r];
                a.z = Cb[(size_t)(j0 + 2) * NN + r];
                a.w = Cb[(size_t)(j0 + 3) * NN + r];
            }
            *(float4*)(smem + r * ROW_STRIDE + lane * 32) = a;
        }
        if (nval > 4) {
            float4 a;
            if (USE_CT) {
                a = *reinterpret_cast<const float4*>(CTb + (size_t)r * QQ + j0 + 4);
            } else {
                a.x = Cb[(size_t)(j0 + 4) * NN + r];
                a.y = Cb[(size_t)(j0 + 5) * NN + r];
                a.z = Cb[(size_t)(j0 + 6) * NN + r];
                a.w = Cb[(size_t)(j0 + 7) * NN + r];
            }
            *(float4*)(smem + r * ROW_STRIDE + lane * 32 + 16) = a;
        }
    }

    // ---- warm rows 64..127 into the LOCAL XCD's L2 (read + keep alive) ----
    float wacc = 0.0f;
    for (int r = 64; r < 128; ++r) {
        if (nval > 0) {
            float4 a;
            if (USE_CT) a = *reinterpret_cast<const float4*>(CTb + (size_t)r * QQ + j0);
            else { a.x = Cb[(size_t)(j0 + 0) * NN + r]; a.y = Cb[(size_t)(j0 + 1) * NN + r];
                   a.z = Cb[(size_t)(j0 + 2) * NN + r]; a.w = Cb[(size_t)(j0 + 3) * NN + r]; }
            wacc += a.x + a.w;
        }
        if (nval > 4) {
            float4 a;
            if (USE_CT) a = *reinterpret_cast<const float4*>(CTb + (size_t)r * QQ + j0 + 4);
            else { a.x = Cb[(size_t)(j0 + 4) * NN + r]; a.y = Cb[(size_t)(j0 + 5) * NN + r];
                   a.z = Cb[(size_t)(j0 + 6) * NN + r]; a.w = Cb[(size_t)(j0 + 7) * NN + r]; }
            wacc += a.x + a.w;
        }
    }
    asm volatile("" :: "v"(wacc));   // keep warm loads live (rule #17)
    __syncthreads();

    double v_[8], spc_[8];
    int path_[8], r4c_[8];
    double u0 = 0.0, u1 = 0.0;
    int c4r0 = -1, c4r1 = -1;
#pragma unroll
    for (int k = 0; k < 8; ++k) { v_[k] = 0.0; r4c_[k] = -1; }

    for (int cur = 0; cur < NN; ++cur) {
#pragma unroll
        for (int k = 0; k < 8; ++k) { spc_[k] = INFINITY; path_[k] = -1; }
        unsigned int sc = 0;
        int sr0 = 0, sr1 = 0;
        double minv = 0.0;
        int i = cur, sink = -1;

        while (true) {
            // ---- cost row i, my 8 columns (LDS for i<64, warmed L2 else) ----
            float c_[8];
            if (i < 64) {
                float4 a  = *(const float4*)(smem + i * ROW_STRIDE + lane * 32);
                float4 a2 = *(const float4*)(smem + i * ROW_STRIDE + lane * 32 + 16);
                c_[0] = a.x;  c_[1] = a.y;  c_[2] = a.z;  c_[3] = a.w;
                c_[4] = a2.x; c_[5] = a2.y; c_[6] = a2.z; c_[7] = a2.w;
            } else if (USE_CT) {
                const float4* p = reinterpret_cast<const float4*>(CTb + (size_t)i * QQ + j0);
                if (nval > 0) {
                    float4 a = p[0];
                    c_[0] = a.x; c_[1] = a.y; c_[2] = a.z; c_[3] = a.w;
                } else { c_[0] = c_[1] = c_[2] = c_[3] = 0.0f; }
                if (nval > 4) {
                    float4 a = p[1];
                    c_[4] = a.x; c_[5] = a.y; c_[6] = a.z; c_[7] = a.w;
                } else { c_[4] = c_[5] = c_[6] = c_[7] = 0.0f; }
            } else {
#pragma unroll
                for (int k = 0; k < 8; ++k)
                    c_[k] = (j0 + k < QQ) ? Cb[(size_t)(j0 + k) * NN + i] : 0.0f;
            }

            // SR[i] = True
            if (i < 64) { if (lane == i) sr0 = 1; }
            else        { if (lane == i - 64) sr1 = 1; }

            // u[i] broadcast — uniform i => readlane
            double ui = (i < 64) ? rl_d(u0, i) : rl_d(u1, i - 64);

            // relax: r = ((min_val + cost[i,j]) - u[i]) - v[j]  (numpy order)
#pragma unroll
            for (int k = 0; k < 8; ++k) {
                double r = ((minv + (double)c_[k]) - ui) - v_[k];
                bool ok = (k < nval) && !((sc >> k) & 1) && (r < spc_[k]);
                if (ok) { spc_[k] = r; path_[k] = i; }
            }

            // masked values for the min (invalid/SC -> +inf)
            double val[8];
#pragma unroll
            for (int k = 0; k < 8; ++k) {
                bool okk = (k < nval) && !((sc >> k) & 1);
                val[k] = okk ? spc_[k] : INFINITY;
            }
            // 3-level tree, strict '<' keeps the earlier index on ties
            double p0 = (val[1] < val[0]) ? val[1] : val[0];
            int    q0 = (val[1] < val[0]) ? 1 : 0;
            double p1 = (val[3] < val[2]) ? val[3] : val[2];
            int    q1 = (val[3] < val[2]) ? 3 : 2;
            double p2 = (val[5] < val[4]) ? val[5] : val[4];
            int    q2 = (val[5] < val[4]) ? 5 : 4;
            double p3 = (val[7] < val[6]) ? val[7] : val[6];
            int    q3 = (val[7] < val[6]) ? 7 : 6;
            double w0 = (p1 < p0) ? p1 : p0;
            int    x0 = (p1 < p0) ? q1 : q0;
            double w1 = (p3 < p2) ? p3 : p2;
            int    x1 = (p3 < p2) ? q3 : q2;
            double lval = (w1 < w0) ? w1 : w0;
            int    lj   = j0 + ((w1 < w0) ? x1 : x0);

            // wave min via DPP v_min_f64 chain; lane 63 holds global min
            double m = lval;
            m = dpp_fmin_step<ROW_SHR1>(m);
            m = dpp_fmin_step<ROW_SHR2>(m);
            m = dpp_fmin_step<ROW_SHR4>(m);
            m = dpp_fmin_step<ROW_SHR8>(m);
            m = dpp_fmin_step<ROW_BC15>(m);
            m = dpp_fmin_step<ROW_BC31>(m);
            double gmin = rl_d(m, 63);

            // first-occurrence tie-break: lowest lane whose lval equals gmin
            unsigned long long mball = __ballot(lval == gmin);
            int winner = __ffsll((long long)mball) - 1;
            int jmin = rl_i(lj, winner);
            double minv_next = rl_d(lval, winner);   // == spc[jmin] bit-exact

            // SC[jmin] = True
            if (lane == (jmin >> 3)) sc |= 1u << (jmin & 7);

            // r4 = row4col[jmin]  (uniform => readlane)
            int kq = jmin & 7;
            int selr; SEL8(r4c_, kq, selr);
            int r4 = rl_i(selr, jmin >> 3);

            minv = minv_next;
            if (r4 < 0) { sink = jmin; break; }
            i = r4;
        }

        // ---- spill spc to LDS for the col4row gather ----
        {
            char* base = smem + SPC_OFF + lane * SPC_LANE_STRIDE;
            double2 d01; d01.x = spc_[0]; d01.y = spc_[1];
            double2 d23; d23.x = spc_[2]; d23.y = spc_[3];
            double2 d45; d45.x = spc_[4]; d45.y = spc_[5];
            double2 d67; d67.x = spc_[6]; d67.y = spc_[7];
            *(double2*)(base +  0) = d01;
            *(double2*)(base + 16) = d23;
            *(double2*)(base + 32) = d45;
            *(double2*)(base + 48) = d67;
        }
        __syncthreads();
        const int g0i = (c4r0 < 0) ? 0 : c4r0;
        const int g1i = (c4r1 < 0) ? 0 : c4r1;
        const double g0 = *(const double*)(smem + spc_addr(g0i));
        const double g1 = *(const double*)(smem + spc_addr(g1i));

        // ---- dual updates (pre-augmentation col4row, exact numpy order) ----
        if (lane == cur) { u0 = u0 + minv; }
        else if (sr0)    { double t = minv - g0; u0 = u0 + t; }
        if (lane + 64 == cur) { u1 = u1 + minv; }
        else if (sr1)         { double t = minv - g1; u1 = u1 + t; }
#pragma unroll
        for (int k = 0; k < 8; ++k) {
            if ((k < nval) && ((sc >> k) & 1)) {
                double t = minv - spc_[k];
                v_[k] = v_[k] - t;
            }
        }
        __syncthreads();   // spc LDS region reused next augmentation

        // ---- augment along alternating path (uniform j walk, readlane) ----
        int j = sink;
        while (true) {
            int kq = j & 7, src = j >> 3;
            int sp; SEL8(path_, kq, sp);
            int i2 = rl_i(sp, src);
            if (lane == src) { SCAT8(r4c_, kq, i2); }   // row4col[j] = i2
            int t2;
            if (i2 < 64) {
                t2 = rl_i(c4r0, i2);
                if (lane == i2) c4r0 = j;
            } else {
                t2 = rl_i(c4r1, i2 - 64);
                if (lane == i2 - 64) c4r1 = j;
            }
            j = t2;
            if (i2 == cur) break;
        }
    }

    // ---- output: rows = sorted assigned-query idx, cols = target idx ----
    int* s_q = (int*)(smem + SQ_OFF);
    s_q[lane] = c4r0;
    s_q[64 + lane] = c4r1;
    __syncthreads();
    int rank0 = 0, rank1 = 0;
    for (int t = 0; t < NN; ++t) {
        int qv = s_q[t];
        rank0 += (qv < c4r0) ? 1 : 0;
        rank1 += (qv < c4r1) ? 1 : 0;
    }
    out_rows[(size_t)b * NN + rank0] = (float)c4r0;
    out_cols[(size_t)b * NN + rank0] = (float)lane;
    out_rows[(size_t)b * NN + rank1] = (float)c4r1;
    out_cols[(size_t)b * NN + rank1] = (float)(64 + lane);
}

// ---------------------------------------------------------------------------
extern "C" void kernel_launch(void* const* d_in, const int* in_sizes, int n_in,
                              void* d_out, int out_size, void* d_ws, size_t ws_size,
                              hipStream_t stream) {
    const float* pb = (const float*)d_in[0];  // pred_boxes     (B,Q,4)
    const float* pk = (const float*)d_in[1];  // pred_keypoints (B,Q,17,2)
    const float* tb = (const float*)d_in[2];  // tgt_boxes      (B,N,4)
    const float* tk = (const float*)d_in[3];  // tgt_keypoints  (B,N,17,2)

    float* outC  = (float*)d_out;                      // (B,Q,N)
    float* orows = outC + (size_t)BB * QQ * NN;        // (B,N)
    float* ocols = orows + (size_t)BB * NN;            // (B,N)

    const size_t ct_bytes = (size_t)BB * NN * QQ * sizeof(float);
    const bool useCT = (ws_size >= ct_bytes);
    float* CT = useCT ? (float*)d_ws : nullptr;

    dim3 grid(QQ, BB);
    cost_kernel<<<grid, 128, 0, stream>>>(pb, pk, tb, tk, outC, CT, useCT ? 1 : 0);

    if (useCT)
        lsa_wave_kernel<true><<<BB, 64, SMEM_BYTES, stream>>>(outC, CT, orows, ocols);
    else
        lsa_wave_kernel<false><<<BB, 64, SMEM_BYTES, stream>>>(outC, nullptr, orows, ocols);
}

// Round 5
// 161.052 us; speedup vs baseline: 2.2143x; 1.8505x over previous
//
#include <hip/hip_runtime.h>
#include <math.h>

#define BB 16
#define QQ 500
#define NN 128
#define KK2 34   // 17 keypoints * 2

// ---------------------------------------------------------------------------
// Kernel 1: cost matrix  C[b][q][n]  (fp32, exact op order of the reference)
// Also writes transposed CT[b][n][q]. UNCHANGED (numerics must stay identical).
// ---------------------------------------------------------------------------
__global__ __launch_bounds__(128) void cost_kernel(
    const float* __restrict__ pb,   // (B,Q,4) cxcywh
    const float* __restrict__ pk,   // (B,Q,17,2)
    const float* __restrict__ tb,   // (B,N,4)
    const float* __restrict__ tk,   // (B,N,17,2)
    float* __restrict__ C,          // (B,Q,N)
    float* __restrict__ CT,         // (B,N,Q) or nullptr
    int writeCT)
{
#pragma clang fp contract(off)
    const int q = blockIdx.x;
    const int b = blockIdx.y;
    const int n = threadIdx.x;

    __shared__ float spb[4];
    __shared__ float spk[KK2];
    if (threadIdx.x < 4)
        spb[threadIdx.x] = pb[((size_t)b * QQ + q) * 4 + threadIdx.x];
    if (threadIdx.x < KK2)
        spk[threadIdx.x] = pk[((size_t)b * QQ + q) * KK2 + threadIdx.x];
    __syncthreads();

    const float pcx = spb[0], pcy = spb[1], pw = spb[2], ph = spb[3];

    const size_t tbase = ((size_t)b * NN + n) * 4;
    const float tcx = tb[tbase + 0];
    const float tcy = tb[tbase + 1];
    const float tw  = tb[tbase + 2];
    const float th  = tb[tbase + 3];

    float cb = fabsf(pcx - tcx);
    cb = cb + fabsf(pcy - tcy);
    cb = cb + fabsf(pw - tw);
    cb = cb + fabsf(ph - th);

    float px0 = pcx - 0.5f * pw;
    float py0 = pcy - 0.5f * ph;
    float px1 = pcx + 0.5f * pw;
    float py1 = pcy + 0.5f * ph;
    px1 = fmaxf(px1, px0 + 1e-4f);
    py1 = fmaxf(py1, py0 + 1e-4f);

    float tx0 = tcx - 0.5f * tw;
    float ty0 = tcy - 0.5f * th;
    float tx1 = tcx + 0.5f * tw;
    float ty1 = tcy + 0.5f * th;
    tx1 = fmaxf(tx1, tx0 + 1e-4f);
    ty1 = fmaxf(ty1, ty0 + 1e-4f);

    const float area_p = (px1 - px0) * (py1 - py0);
    const float area_t = (tx1 - tx0) * (ty1 - ty0);

    const float ltx = fmaxf(px0, tx0);
    const float lty = fmaxf(py0, ty0);
    const float rbx = fminf(px1, tx1);
    const float rby = fminf(py1, ty1);
    const float wx = fmaxf(rbx - ltx, 0.0f);
    const float wy = fmaxf(rby - lty, 0.0f);
    const float inter = wx * wy;
    const float uni = (area_p + area_t) - inter;
    const float iou = inter / uni;

    const float ex0 = fminf(px0, tx0);
    const float ey0 = fminf(py0, ty0);
    const float ex1 = fmaxf(px1, tx1);
    const float ey1 = fmaxf(py1, ty1);
    const float ewx = fmaxf(ex1 - ex0, 0.0f);
    const float ewy = fmaxf(ey1 - ey0, 0.0f);
    const float enc = ewx * ewy;

    const float giou = iou - (enc - uni) / enc;
    const float cg = -giou;

    const size_t kbase = ((size_t)b * NN + n) * KK2;
    float ck = 0.0f;
    for (int k = 0; k < KK2; ++k)
        ck = ck + fabsf(spk[k] - tk[kbase + k]);

    const float Cv = (5.0f * cb + 2.0f * cg) + ck;

    C[((size_t)b * QQ + q) * NN + n] = Cv;
    if (writeCT)
        CT[((size_t)b * NN + n) * QQ + q] = Cv;
}

// uniform-lane readlane helpers (scalar pipe, no LDS)
__device__ __forceinline__ int rl_i(int v, int l) {
    return __builtin_amdgcn_readlane(v, l);
}
__device__ __forceinline__ double rl_d(double v, int l) {
    int lo = __builtin_amdgcn_readlane(__double2loint(v), l);
    int hi = __builtin_amdgcn_readlane(__double2hiint(v), l);
    return __hiloint2double(hi, lo);
}

// one DPP min step on f64 (two 32-bit dpp movs + v_min_f64)
template <int CTRL>
__device__ __forceinline__ double dpp_fmin_step(double x) {
    int lo = __double2loint(x);
    int hi = __double2hiint(x);
    int nlo = __builtin_amdgcn_update_dpp(lo, lo, CTRL, 0xF, 0xF, false);
    int nhi = __builtin_amdgcn_update_dpp(hi, hi, CTRL, 0xF, 0xF, false);
    return fmin(__hiloint2double(nhi, nlo), x);
}
#define ROW_SHR1  0x111
#define ROW_SHR2  0x112
#define ROW_SHR4  0x114
#define ROW_SHR8  0x118
#define ROW_BC15  0x142
#define ROW_BC31  0x143

// constant-index select/scatter on 8-arrays (register-resident, rule #20)
#define SEL8(arr, kq, out) do { \
    out = arr[0]; \
    if ((kq)==1) out = arr[1]; if ((kq)==2) out = arr[2]; if ((kq)==3) out = arr[3]; \
    if ((kq)==4) out = arr[4]; if ((kq)==5) out = arr[5]; if ((kq)==6) out = arr[6]; \
    if ((kq)==7) out = arr[7]; } while (0)

#define SCAT8(arr, kq, val) do { \
    if ((kq)==0) arr[0] = (val); if ((kq)==1) arr[1] = (val); \
    if ((kq)==2) arr[2] = (val); if ((kq)==3) arr[3] = (val); \
    if ((kq)==4) arr[4] = (val); if ((kq)==5) arr[5] = (val); \
    if ((kq)==6) arr[6] = (val); if ((kq)==7) arr[7] = (val); } while (0)

// ---------------------------------------------------------------------------
// Kernel 2: per-batch rectangular LSA (JV / shortest augmenting path) on
// cost[b].T (N=128 rows x Q=500 cols). Row-reduction + greedy init (standard
// JV), then SAP for the remaining rows. Any exact-optimal assignment matches
// the reference (unique optimum for continuous random data).
// ONE WAVE per batch. Lane l owns columns j = 8l..8l+7 and rows l, l+64.
// Wave argmin: f64 reduced costs are >= 0, so pack the 9-bit column index
// into the low mantissa bits -> one DPP v_min_f64 chain gives value+argmin
// (ties in the upper 55 bits resolve to smallest j, same as np.argmin).
// ---------------------------------------------------------------------------
template <bool USE_CT>
__global__ __launch_bounds__(64) void lsa_wave_kernel(
    const float* __restrict__ C,    // (B,Q,N)
    const float* __restrict__ CT,   // (B,N,Q) or nullptr
    float* __restrict__ out_rows,   // (B,N) as float
    float* __restrict__ out_cols)   // (B,N) as float
{
#pragma clang fp contract(off)
    const int b = blockIdx.x;
    const int lane = threadIdx.x;

    __shared__ double s_spc[64 * 10];   // stride 10 doubles (80 B) per lane
    __shared__ int s_q[NN];

    const float* Cb  = C + (size_t)b * QQ * NN;
    const float* CTb = USE_CT ? (CT + (size_t)b * NN * QQ) : nullptr;

    const int j0 = lane * 8;
    const int nval = (QQ - j0 < 0) ? 0 : ((QQ - j0 > 8) ? 8 : (QQ - j0));

    double v_[8], spc_[8];
    int path_[8], r4c_[8];
    double u0, u1;
    int c4r0 = -1, c4r1 = -1;
#pragma unroll
    for (int k = 0; k < 8; ++k) { v_[k] = 0.0; r4c_[k] = -1; }

    // ---- Phase A: row minima (row reduction). Lane l scans rows l, l+64.
    // Contiguous per-lane walk of CT also warms the whole slice into L2. ----
    float m0 = INFINITY, m1 = INFINITY;
    int jm0 = 0, jm1 = 0;
#pragma unroll 4
    for (int q = 0; q < QQ; ++q) {
        float a, c;
        if (USE_CT) {
            a = CTb[(size_t)lane * QQ + q];
            c = CTb[(size_t)(64 + lane) * QQ + q];
        } else {
            a = Cb[(size_t)q * NN + lane];
            c = Cb[(size_t)q * NN + 64 + lane];
        }
        if (a < m0) { m0 = a; jm0 = q; }
        if (c < m1) { m1 = c; jm1 = q; }
    }
    u0 = (double)m0;
    u1 = (double)m1;

    // ---- Phase B: greedy matching on row minima (sequential, uniform) ----
    for (int i = 0; i < NN; ++i) {
        int jm = (i < 64) ? rl_i(jm0, i) : rl_i(jm1, i - 64);
        int kq = jm & 7;
        int selr; SEL8(r4c_, kq, selr);
        int occ = rl_i(selr, jm >> 3);
        if (occ < 0) {
            if (lane == (jm >> 3)) { SCAT8(r4c_, kq, i); }
            if (i < 64) { if (lane == i) c4r0 = jm; }
            else        { if (lane == i - 64) c4r1 = jm; }
        }
    }

    // ---- Phase C: shortest augmenting path for the unmatched rows ----
    for (int cur = 0; cur < NN; ++cur) {
        int already = (cur < 64) ? rl_i(c4r0, cur) : rl_i(c4r1, cur - 64);
        if (already >= 0) continue;

#pragma unroll
        for (int k = 0; k < 8; ++k) { spc_[k] = INFINITY; path_[k] = -1; }
        unsigned int sc = 0;
        int sr0 = 0, sr1 = 0;
        double minv = 0.0;
        int i = cur, sink = -1;

        while (true) {
            // ---- cost row i, my 8 columns (coalesced float4 from CT) ----
            float c_[8];
            if (USE_CT) {
                const float4* p = reinterpret_cast<const float4*>(CTb + (size_t)i * QQ + j0);
                if (nval > 0) {
                    float4 a = p[0];
                    c_[0] = a.x; c_[1] = a.y; c_[2] = a.z; c_[3] = a.w;
                } else { c_[0] = c_[1] = c_[2] = c_[3] = 0.0f; }
                if (nval > 4) {
                    float4 a = p[1];
                    c_[4] = a.x; c_[5] = a.y; c_[6] = a.z; c_[7] = a.w;
                } else { c_[4] = c_[5] = c_[6] = c_[7] = 0.0f; }
            } else {
#pragma unroll
                for (int k = 0; k < 8; ++k)
                    c_[k] = (j0 + k < QQ) ? Cb[(size_t)(j0 + k) * NN + i] : 0.0f;
            }

            // SR[i] = True
            if (i < 64) { if (lane == i) sr0 = 1; }
            else        { if (lane == i - 64) sr1 = 1; }

            // u[i] broadcast — uniform i => readlane
            double ui = (i < 64) ? rl_d(u0, i) : rl_d(u1, i - 64);

            // relax: r = ((min_val + cost[i,j]) - u[i]) - v[j]
#pragma unroll
            for (int k = 0; k < 8; ++k) {
                double r = ((minv + (double)c_[k]) - ui) - v_[k];
                bool ok = (k < nval) && !((sc >> k) & 1) && (r < spc_[k]);
                if (ok) { spc_[k] = r; path_[k] = i; }
            }

            // masked values for the min (invalid/SC -> +inf)
            double val[8];
#pragma unroll
            for (int k = 0; k < 8; ++k) {
                bool okk = (k < nval) && !((sc >> k) & 1);
                val[k] = okk ? spc_[k] : INFINITY;
            }
            // 3-level tree, strict '<' keeps the earlier index on ties
            double p0 = (val[1] < val[0]) ? val[1] : val[0];
            int    q0 = (val[1] < val[0]) ? 1 : 0;
            double p1 = (val[3] < val[2]) ? val[3] : val[2];
            int    q1 = (val[3] < val[2]) ? 3 : 2;
            double p2 = (val[5] < val[4]) ? val[5] : val[4];
            int    q2 = (val[5] < val[4]) ? 5 : 4;
            double p3 = (val[7] < val[6]) ? val[7] : val[6];
            int    q3 = (val[7] < val[6]) ? 7 : 6;
            double w0 = (p1 < p0) ? p1 : p0;
            int    x0 = (p1 < p0) ? q1 : q0;
            double w1 = (p3 < p2) ? p3 : p2;
            int    x1 = (p3 < p2) ? q3 : q2;
            double lval = (w1 < w0) ? w1 : w0;
            int    lj   = j0 + ((w1 < w0) ? x1 : x0);

            // pack 9-bit column index into low mantissa bits (spc >= 0, finite)
            long long kb;
            if (lval < INFINITY)
                kb = (__double_as_longlong(lval) & ~0x1FFLL) | (long long)lj;
            else
                kb = 0x7FF0000000000000LL;   // +inf, index bits clear
            double kd = __longlong_as_double(kb);

            // wave min via DPP v_min_f64 chain; lane 63 holds global min key
            double m = kd;
            m = dpp_fmin_step<ROW_SHR1>(m);
            m = dpp_fmin_step<ROW_SHR2>(m);
            m = dpp_fmin_step<ROW_SHR4>(m);
            m = dpp_fmin_step<ROW_SHR8>(m);
            m = dpp_fmin_step<ROW_BC15>(m);
            m = dpp_fmin_step<ROW_BC31>(m);
            double gk = rl_d(m, 63);

            int jmin   = (int)(__double_as_longlong(gk) & 0x1FFLL);
            int winner = jmin >> 3;
            double minv_next = rl_d(lval, winner);   // exact spc[jmin]

            // SC[jmin] = True
            if (lane == winner) sc |= 1u << (jmin & 7);

            // r4 = row4col[jmin]  (uniform => readlane)
            int kq = jmin & 7;
            int selr; SEL8(r4c_, kq, selr);
            int r4 = rl_i(selr, winner);

            minv = minv_next;
            if (r4 < 0) { sink = jmin; break; }
            i = r4;
        }

        // ---- spill spc to LDS for the col4row gather ----
        {
            double* base = s_spc + lane * 10;
            double2 d01; d01.x = spc_[0]; d01.y = spc_[1];
            double2 d23; d23.x = spc_[2]; d23.y = spc_[3];
            double2 d45; d45.x = spc_[4]; d45.y = spc_[5];
            double2 d67; d67.x = spc_[6]; d67.y = spc_[7];
            *(double2*)(base + 0) = d01;
            *(double2*)(base + 2) = d23;
            *(double2*)(base + 4) = d45;
            *(double2*)(base + 6) = d67;
        }
        __syncthreads();
        const int g0i = (c4r0 < 0) ? 0 : c4r0;
        const int g1i = (c4r1 < 0) ? 0 : c4r1;
        const double g0 = s_spc[(g0i >> 3) * 10 + (g0i & 7)];
        const double g1 = s_spc[(g1i >> 3) * 10 + (g1i & 7)];

        // ---- dual updates (pre-augmentation col4row) ----
        if (lane == cur) { u0 = u0 + minv; }
        else if (sr0)    { double t = minv - g0; u0 = u0 + t; }
        if (lane + 64 == cur) { u1 = u1 + minv; }
        else if (sr1)         { double t = minv - g1; u1 = u1 + t; }
#pragma unroll
        for (int k = 0; k < 8; ++k) {
            if ((k < nval) && ((sc >> k) & 1)) {
                double t = minv - spc_[k];
                v_[k] = v_[k] - t;
            }
        }
        __syncthreads();   // spc LDS region reused next augmentation

        // ---- augment along alternating path (uniform j walk, readlane) ----
        int j = sink;
        while (true) {
            int kq = j & 7, src = j >> 3;
            int sp; SEL8(path_, kq, sp);
            int i2 = rl_i(sp, src);
            if (lane == src) { SCAT8(r4c_, kq, i2); }   // row4col[j] = i2
            int t2;
            if (i2 < 64) {
                t2 = rl_i(c4r0, i2);
                if (lane == i2) c4r0 = j;
            } else {
                t2 = rl_i(c4r1, i2 - 64);
                if (lane == i2 - 64) c4r1 = j;
            }
            j = t2;
            if (i2 == cur) break;
        }
    }

    // ---- output: rows = sorted assigned-query idx, cols = target idx ----
    s_q[lane] = c4r0;
    s_q[64 + lane] = c4r1;
    __syncthreads();
    int rank0 = 0, rank1 = 0;
    for (int t = 0; t < NN; ++t) {
        int qv = s_q[t];
        rank0 += (qv < c4r0) ? 1 : 0;
        rank1 += (qv < c4r1) ? 1 : 0;
    }
    out_rows[(size_t)b * NN + rank0] = (float)c4r0;
    out_cols[(size_t)b * NN + rank0] = (float)lane;
    out_rows[(size_t)b * NN + rank1] = (float)c4r1;
    out_cols[(size_t)b * NN + rank1] = (float)(64 + lane);
}

// ---------------------------------------------------------------------------
extern "C" void kernel_launch(void* const* d_in, const int* in_sizes, int n_in,
                              void* d_out, int out_size, void* d_ws, size_t ws_size,
                              hipStream_t stream) {
    const float* pb = (const float*)d_in[0];  // pred_boxes     (B,Q,4)
    const float* pk = (const float*)d_in[1];  // pred_keypoints (B,Q,17,2)
    const float* tb = (const float*)d_in[2];  // tgt_boxes      (B,N,4)
    const float* tk = (const float*)d_in[3];  // tgt_keypoints  (B,N,17,2)

    float* outC  = (float*)d_out;                      // (B,Q,N)
    float* orows = outC + (size_t)BB * QQ * NN;        // (B,N)
    float* ocols = orows + (size_t)BB * NN;            // (B,N)

    const size_t ct_bytes = (size_t)BB * NN * QQ * sizeof(float);
    const bool useCT = (ws_size >= ct_bytes);
    float* CT = useCT ? (float*)d_ws : nullptr;

    dim3 grid(QQ, BB);
    cost_kernel<<<grid, 128, 0, stream>>>(pb, pk, tb, tk, outC, CT, useCT ? 1 : 0);

    if (useCT)
        lsa_wave_kernel<true><<<BB, 64, 0, stream>>>(outC, CT, orows, ocols);
    else
        lsa_wave_kernel<false><<<BB, 64, 0, stream>>>(outC, nullptr, orows, ocols);
}

// Round 6
// 129.285 us; speedup vs baseline: 2.7584x; 1.2457x over previous
//
#include <hip/hip_runtime.h>
#include <math.h>

#define BB 16
#define QQ 500
#define NN 128
#define KK2 34   // 17 keypoints * 2

// ---------------------------------------------------------------------------
// Kernel 1: cost matrix  C[b][q][n]  (fp32, exact op order of the reference)
// Also writes transposed CT[b][n][q]. UNCHANGED (numerics must stay identical).
// ---------------------------------------------------------------------------
__global__ __launch_bounds__(128) void cost_kernel(
    const float* __restrict__ pb,   // (B,Q,4) cxcywh
    const float* __restrict__ pk,   // (B,Q,17,2)
    const float* __restrict__ tb,   // (B,N,4)
    const float* __restrict__ tk,   // (B,N,17,2)
    float* __restrict__ C,          // (B,Q,N)
    float* __restrict__ CT,         // (B,N,Q) or nullptr
    int writeCT)
{
#pragma clang fp contract(off)
    const int q = blockIdx.x;
    const int b = blockIdx.y;
    const int n = threadIdx.x;

    __shared__ float spb[4];
    __shared__ float spk[KK2];
    if (threadIdx.x < 4)
        spb[threadIdx.x] = pb[((size_t)b * QQ + q) * 4 + threadIdx.x];
    if (threadIdx.x < KK2)
        spk[threadIdx.x] = pk[((size_t)b * QQ + q) * KK2 + threadIdx.x];
    __syncthreads();

    const float pcx = spb[0], pcy = spb[1], pw = spb[2], ph = spb[3];

    const size_t tbase = ((size_t)b * NN + n) * 4;
    const float tcx = tb[tbase + 0];
    const float tcy = tb[tbase + 1];
    const float tw  = tb[tbase + 2];
    const float th  = tb[tbase + 3];

    float cb = fabsf(pcx - tcx);
    cb = cb + fabsf(pcy - tcy);
    cb = cb + fabsf(pw - tw);
    cb = cb + fabsf(ph - th);

    float px0 = pcx - 0.5f * pw;
    float py0 = pcy - 0.5f * ph;
    float px1 = pcx + 0.5f * pw;
    float py1 = pcy + 0.5f * ph;
    px1 = fmaxf(px1, px0 + 1e-4f);
    py1 = fmaxf(py1, py0 + 1e-4f);

    float tx0 = tcx - 0.5f * tw;
    float ty0 = tcy - 0.5f * th;
    float tx1 = tcx + 0.5f * tw;
    float ty1 = tcy + 0.5f * th;
    tx1 = fmaxf(tx1, tx0 + 1e-4f);
    ty1 = fmaxf(ty1, ty0 + 1e-4f);

    const float area_p = (px1 - px0) * (py1 - py0);
    const float area_t = (tx1 - tx0) * (ty1 - ty0);

    const float ltx = fmaxf(px0, tx0);
    const float lty = fmaxf(py0, ty0);
    const float rbx = fminf(px1, tx1);
    const float rby = fminf(py1, ty1);
    const float wx = fmaxf(rbx - ltx, 0.0f);
    const float wy = fmaxf(rby - lty, 0.0f);
    const float inter = wx * wy;
    const float uni = (area_p + area_t) - inter;
    const float iou = inter / uni;

    const float ex0 = fminf(px0, tx0);
    const float ey0 = fminf(py0, ty0);
    const float ex1 = fmaxf(px1, tx1);
    const float ey1 = fmaxf(py1, ty1);
    const float ewx = fmaxf(ex1 - ex0, 0.0f);
    const float ewy = fmaxf(ey1 - ey0, 0.0f);
    const float enc = ewx * ewy;

    const float giou = iou - (enc - uni) / enc;
    const float cg = -giou;

    const size_t kbase = ((size_t)b * NN + n) * KK2;
    float ck = 0.0f;
    for (int k = 0; k < KK2; ++k)
        ck = ck + fabsf(spk[k] - tk[kbase + k]);

    const float Cv = (5.0f * cb + 2.0f * cg) + ck;

    C[((size_t)b * QQ + q) * NN + n] = Cv;
    if (writeCT)
        CT[((size_t)b * NN + n) * QQ + q] = Cv;
}

// uniform-lane readlane helpers (scalar pipe, no LDS)
__device__ __forceinline__ int rl_i(int v, int l) {
    return __builtin_amdgcn_readlane(v, l);
}
__device__ __forceinline__ double rl_d(double v, int l) {
    int lo = __builtin_amdgcn_readlane(__double2loint(v), l);
    int hi = __builtin_amdgcn_readlane(__double2hiint(v), l);
    return __hiloint2double(hi, lo);
}

// one DPP min step on f64 (two 32-bit dpp movs + v_min_f64)
template <int CTRL>
__device__ __forceinline__ double dpp_fmin_step(double x) {
    int lo = __double2loint(x);
    int hi = __double2hiint(x);
    int nlo = __builtin_amdgcn_update_dpp(lo, lo, CTRL, 0xF, 0xF, false);
    int nhi = __builtin_amdgcn_update_dpp(hi, hi, CTRL, 0xF, 0xF, false);
    return fmin(__hiloint2double(nhi, nlo), x);
}
#define ROW_SHR1  0x111
#define ROW_SHR2  0x112
#define ROW_SHR4  0x114
#define ROW_SHR8  0x118
#define ROW_BC15  0x142
#define ROW_BC31  0x143

__device__ __forceinline__ double dpp_fmin_wave(double x) {
    x = dpp_fmin_step<ROW_SHR1>(x);
    x = dpp_fmin_step<ROW_SHR2>(x);
    x = dpp_fmin_step<ROW_SHR4>(x);
    x = dpp_fmin_step<ROW_SHR8>(x);
    x = dpp_fmin_step<ROW_BC15>(x);
    x = dpp_fmin_step<ROW_BC31>(x);
    return x;   // lane 63 holds the wave min
}

// constant-index select/scatter on 8-arrays (register-resident, rule #20)
#define SEL8(arr, kq, out) do { \
    out = arr[0]; \
    if ((kq)==1) out = arr[1]; if ((kq)==2) out = arr[2]; if ((kq)==3) out = arr[3]; \
    if ((kq)==4) out = arr[4]; if ((kq)==5) out = arr[5]; if ((kq)==6) out = arr[6]; \
    if ((kq)==7) out = arr[7]; } while (0)

#define SCAT8(arr, kq, val) do { \
    if ((kq)==0) arr[0] = (val); if ((kq)==1) arr[1] = (val); \
    if ((kq)==2) arr[2] = (val); if ((kq)==3) arr[3] = (val); \
    if ((kq)==4) arr[4] = (val); if ((kq)==5) arr[5] = (val); \
    if ((kq)==6) arr[6] = (val); if ((kq)==7) arr[7] = (val); } while (0)

// ---------------------------------------------------------------------------
// Kernel 1.5: per-row min + first-occurrence argmin of CT rows.
// One block (64 lanes) per (row, batch): fully parallel (2048 blocks).
// Packs exact f64(min)|9-bit-index (f32->f64 leaves 29 zero mantissa bits,
// so OR of the index is exact and the DPP f64 min resolves value+argmin).
// ---------------------------------------------------------------------------
__global__ __launch_bounds__(64) void rowmin_kernel(
    const float* __restrict__ CT,   // (B,N,Q)
    double* __restrict__ rm)        // (B,N) packed f64(min)|argmin
{
    const int n = blockIdx.x;
    const int b = blockIdx.y;
    const int lane = threadIdx.x;

    const float4* r4 = reinterpret_cast<const float4*>(CT + ((size_t)b * NN + n) * QQ);

    float m = INFINITY;
    int jm = 0;
    {
        float4 a = r4[lane];             // elements 4*lane .. 4*lane+3
        int base = lane * 4;
        if (a.x < m) { m = a.x; jm = base + 0; }
        if (a.y < m) { m = a.y; jm = base + 1; }
        if (a.z < m) { m = a.z; jm = base + 2; }
        if (a.w < m) { m = a.w; jm = base + 3; }
    }
    if (lane < 61) {                     // 500/4 = 125 float4s total
        float4 a = r4[64 + lane];
        int base = (64 + lane) * 4;
        if (a.x < m) { m = a.x; jm = base + 0; }
        if (a.y < m) { m = a.y; jm = base + 1; }
        if (a.z < m) { m = a.z; jm = base + 2; }
        if (a.w < m) { m = a.w; jm = base + 3; }
    }

    long long kb = __double_as_longlong((double)m) | (long long)jm;
    double kd = dpp_fmin_wave(__longlong_as_double(kb));
    if (lane == 63)
        rm[(size_t)b * NN + n] = kd;
}

// ---------------------------------------------------------------------------
// Kernel 2: per-batch rectangular LSA (JV / shortest augmenting path) on
// cost[b].T (N=128 rows x Q=500 cols). Row-reduction + greedy init, then SAP.
// Any exact-optimal assignment matches the reference (unique optimum).
// ONE WAVE per batch. Lane l owns columns j = 8l..8l+7 and rows l, l+64.
// spc entries carry their 9-bit column index in the low mantissa bits
// permanently -> mask + 7 v_min_f64 local tree + DPP chain gives
// (value, argmin) with zero index-tracking selects; minv == spc[jmin] exactly.
// ---------------------------------------------------------------------------
template <bool USE_CT, bool PRE>
__global__ __launch_bounds__(64) void lsa_wave_kernel(
    const float* __restrict__ C,    // (B,Q,N)
    const float* __restrict__ CT,   // (B,N,Q) or nullptr
    const double* __restrict__ rm,  // (B,N) packed rowmin or nullptr
    float* __restrict__ out_rows,   // (B,N) as float
    float* __restrict__ out_cols)   // (B,N) as float
{
#pragma clang fp contract(off)
    const int b = blockIdx.x;
    const int lane = threadIdx.x;

    __shared__ double s_spc[64 * 10];   // stride 10 doubles (80 B) per lane
    __shared__ int s_q[NN];

    const float* Cb  = C + (size_t)b * QQ * NN;
    const float* CTb = USE_CT ? (CT + (size_t)b * NN * QQ) : nullptr;

    const int j0 = lane * 8;
    const int nval = (QQ - j0 < 0) ? 0 : ((QQ - j0 > 8) ? 8 : (QQ - j0));

    double v_[8], spc_[8];
    int path_[8], r4c_[8];
    double u0, u1;
    int c4r0 = -1, c4r1 = -1;
    int jm0, jm1;
#pragma unroll
    for (int k = 0; k < 8; ++k) { v_[k] = 0.0; r4c_[k] = -1; }

    // ---- Phase A: row minima ----
    if (PRE) {
        const long long p0 = __double_as_longlong(rm[(size_t)b * NN + lane]);
        const long long p1 = __double_as_longlong(rm[(size_t)b * NN + 64 + lane]);
        u0 = __longlong_as_double(p0 & ~0x1FFLL);
        u1 = __longlong_as_double(p1 & ~0x1FFLL);
        jm0 = (int)(p0 & 0x1FF);
        jm1 = (int)(p1 & 0x1FF);
        if (USE_CT) {
            // coalesced warm pass: pull this batch's CT slice into local L2
            const float4* w4 = reinterpret_cast<const float4*>(CTb);
            float4 acc; acc.x = acc.y = acc.z = acc.w = 0.0f;
#pragma unroll 8
            for (int t = lane; t < (NN * QQ) / 4; t += 64) {
                float4 a = w4[t];
                acc.x += a.x; acc.y += a.y; acc.z += a.z; acc.w += a.w;
            }
            asm volatile("" :: "v"(acc.x), "v"(acc.y), "v"(acc.z), "v"(acc.w));
        }
    } else {
        float m0 = INFINITY, m1 = INFINITY;
        jm0 = 0; jm1 = 0;
#pragma unroll 4
        for (int q = 0; q < QQ; ++q) {
            float a, c;
            if (USE_CT) {
                a = CTb[(size_t)lane * QQ + q];
                c = CTb[(size_t)(64 + lane) * QQ + q];
            } else {
                a = Cb[(size_t)q * NN + lane];
                c = Cb[(size_t)q * NN + 64 + lane];
            }
            if (a < m0) { m0 = a; jm0 = q; }
            if (c < m1) { m1 = c; jm1 = q; }
        }
        u0 = (double)m0;
        u1 = (double)m1;
    }

    // ---- Phase B: greedy matching on row minima (sequential, uniform) ----
    for (int i = 0; i < NN; ++i) {
        int jm = (i < 64) ? rl_i(jm0, i) : rl_i(jm1, i - 64);
        int kq = jm & 7;
        int selr; SEL8(r4c_, kq, selr);
        int occ = rl_i(selr, jm >> 3);
        if (occ < 0) {
            if (lane == (jm >> 3)) { SCAT8(r4c_, kq, i); }
            if (i < 64) { if (lane == i) c4r0 = jm; }
            else        { if (lane == i - 64) c4r1 = jm; }
        }
    }

    // ---- Phase C: shortest augmenting path for the unmatched rows ----
    for (int cur = 0; cur < NN; ++cur) {
        int already = (cur < 64) ? rl_i(c4r0, cur) : rl_i(c4r1, cur - 64);
        if (already >= 0) continue;

        const double INF = INFINITY;
#pragma unroll
        for (int k = 0; k < 8; ++k) { spc_[k] = INF; path_[k] = -1; }
        unsigned int sc = 0;
        int sr0 = 0, sr1 = 0;
        double minv = 0.0;
        int i = cur, sink = -1;

        while (true) {
            // ---- cost row i, my 8 columns (coalesced float4 from CT) ----
            float c_[8];
            if (USE_CT) {
                const float4* p = reinterpret_cast<const float4*>(CTb + (size_t)i * QQ + j0);
                if (nval > 0) {
                    float4 a = p[0];
                    c_[0] = a.x; c_[1] = a.y; c_[2] = a.z; c_[3] = a.w;
                } else { c_[0] = c_[1] = c_[2] = c_[3] = 0.0f; }
                if (nval > 4) {
                    float4 a = p[1];
                    c_[4] = a.x; c_[5] = a.y; c_[6] = a.z; c_[7] = a.w;
                } else { c_[4] = c_[5] = c_[6] = c_[7] = 0.0f; }
            } else {
#pragma unroll
                for (int k = 0; k < 8; ++k)
                    c_[k] = (j0 + k < QQ) ? Cb[(size_t)(j0 + k) * NN + i] : 0.0f;
            }

            // SR[i] = True
            if (i < 64) { if (lane == i) sr0 = 1; }
            else        { if (lane == i - 64) sr1 = 1; }

            // u[i] broadcast — uniform i => readlane
            double ui = (i < 64) ? rl_d(u0, i) : rl_d(u1, i - 64);
            double s = minv - ui;   // wave-uniform

            // relax + pack column index into low mantissa bits
#pragma unroll
            for (int k = 0; k < 8; ++k) {
                double r = (s + (double)c_[k]) - v_[k];
                long long rb = (__double_as_longlong(r) & ~0x1FFLL)
                             | (long long)(j0 + k);
                double rp = __longlong_as_double(rb);
                bool ok = (k < nval) && !((sc >> k) & 1) && (rp < spc_[k]);
                if (ok) { spc_[k] = rp; path_[k] = i; }
            }

            // local min: mask (SC/invalid -> inf) + pure fmin tree (no idx sel)
            double val[8];
#pragma unroll
            for (int k = 0; k < 8; ++k) {
                bool okk = (k < nval) && !((sc >> k) & 1);
                val[k] = okk ? spc_[k] : INF;
            }
            double t01 = fmin(val[0], val[1]);
            double t23 = fmin(val[2], val[3]);
            double t45 = fmin(val[4], val[5]);
            double t67 = fmin(val[6], val[7]);
            double lmin = fmin(fmin(t01, t23), fmin(t45, t67));

            // wave min via DPP chain; lane 63 holds global packed min
            double gk = rl_d(dpp_fmin_wave(lmin), 63);

            int jmin   = (int)(__double_as_longlong(gk) & 0x1FFLL);
            int winner = jmin >> 3;

            // SC[jmin] = True
            if (lane == winner) sc |= 1u << (jmin & 7);

            // r4 = row4col[jmin]  (uniform => readlane)
            int kq = jmin & 7;
            int selr; SEL8(r4c_, kq, selr);
            int r4 = rl_i(selr, winner);

            minv = gk;              // == spc[jmin] exactly (packed)
            if (r4 < 0) { sink = jmin; break; }
            i = r4;
        }

        // ---- spill spc to LDS for the col4row gather ----
        {
            double* base = s_spc + lane * 10;
            double2 d01; d01.x = spc_[0]; d01.y = spc_[1];
            double2 d23; d23.x = spc_[2]; d23.y = spc_[3];
            double2 d45; d45.x = spc_[4]; d45.y = spc_[5];
            double2 d67; d67.x = spc_[6]; d67.y = spc_[7];
            *(double2*)(base + 0) = d01;
            *(double2*)(base + 2) = d23;
            *(double2*)(base + 4) = d45;
            *(double2*)(base + 6) = d67;
        }
        __syncthreads();
        const int g0i = (c4r0 < 0) ? 0 : c4r0;
        const int g1i = (c4r1 < 0) ? 0 : c4r1;
        const double g0 = s_spc[(g0i >> 3) * 10 + (g0i & 7)];
        const double g1 = s_spc[(g1i >> 3) * 10 + (g1i & 7)];

        // ---- dual updates (pre-augmentation col4row) ----
        if (lane == cur) { u0 = u0 + minv; }
        else if (sr0)    { double t = minv - g0; u0 = u0 + t; }
        if (lane + 64 == cur) { u1 = u1 + minv; }
        else if (sr1)         { double t = minv - g1; u1 = u1 + t; }
#pragma unroll
        for (int k = 0; k < 8; ++k) {
            if ((k < nval) && ((sc >> k) & 1)) {
                double t = minv - spc_[k];
                v_[k] = v_[k] - t;
            }
        }
        __syncthreads();   // spc LDS region reused next augmentation

        // ---- augment along alternating path (uniform j walk, readlane) ----
        int j = sink;
        while (true) {
            int kq = j & 7, src = j >> 3;
            int sp; SEL8(path_, kq, sp);
            int i2 = rl_i(sp, src);
            if (lane == src) { SCAT8(r4c_, kq, i2); }   // row4col[j] = i2
            int t2;
            if (i2 < 64) {
                t2 = rl_i(c4r0, i2);
                if (lane == i2) c4r0 = j;
            } else {
                t2 = rl_i(c4r1, i2 - 64);
                if (lane == i2 - 64) c4r1 = j;
            }
            j = t2;
            if (i2 == cur) break;
        }
    }

    // ---- output: rows = sorted assigned-query idx, cols = target idx ----
    s_q[lane] = c4r0;
    s_q[64 + lane] = c4r1;
    __syncthreads();
    int rank0 = 0, rank1 = 0;
    for (int t = 0; t < NN; ++t) {
        int qv = s_q[t];
        rank0 += (qv < c4r0) ? 1 : 0;
        rank1 += (qv < c4r1) ? 1 : 0;
    }
    out_rows[(size_t)b * NN + rank0] = (float)c4r0;
    out_cols[(size_t)b * NN + rank0] = (float)lane;
    out_rows[(size_t)b * NN + rank1] = (float)c4r1;
    out_cols[(size_t)b * NN + rank1] = (float)(64 + lane);
}

// ---------------------------------------------------------------------------
extern "C" void kernel_launch(void* const* d_in, const int* in_sizes, int n_in,
                              void* d_out, int out_size, void* d_ws, size_t ws_size,
                              hipStream_t stream) {
    const float* pb = (const float*)d_in[0];  // pred_boxes     (B,Q,4)
    const float* pk = (const float*)d_in[1];  // pred_keypoints (B,Q,17,2)
    const float* tb = (const float*)d_in[2];  // tgt_boxes      (B,N,4)
    const float* tk = (const float*)d_in[3];  // tgt_keypoints  (B,N,17,2)

    float* outC  = (float*)d_out;                      // (B,Q,N)
    float* orows = outC + (size_t)BB * QQ * NN;        // (B,N)
    float* ocols = orows + (size_t)BB * NN;            // (B,N)

    const size_t ct_bytes = (size_t)BB * NN * QQ * sizeof(float);  // 4,096,000
    const size_t rm_bytes = (size_t)BB * NN * sizeof(double);      // 16,384
    const bool useCT = (ws_size >= ct_bytes);
    const bool pre   = (ws_size >= ct_bytes + rm_bytes);
    float*  CT = useCT ? (float*)d_ws : nullptr;
    double* RM = pre ? (double*)((char*)d_ws + ct_bytes) : nullptr;

    dim3 grid(QQ, BB);
    cost_kernel<<<grid, 128, 0, stream>>>(pb, pk, tb, tk, outC, CT, useCT ? 1 : 0);

    if (pre) {
        rowmin_kernel<<<dim3(NN, BB), 64, 0, stream>>>(CT, RM);
        lsa_wave_kernel<true, true><<<BB, 64, 0, stream>>>(outC, CT, RM, orows, ocols);
    } else if (useCT) {
        lsa_wave_kernel<true, false><<<BB, 64, 0, stream>>>(outC, CT, nullptr, orows, ocols);
    } else {
        lsa_wave_kernel<false, false><<<BB, 64, 0, stream>>>(outC, nullptr, nullptr, orows, ocols);
    }
}

// Round 9
// 128.333 us; speedup vs baseline: 2.7789x; 1.0074x over previous
//
#include <hip/hip_runtime.h>
#include <math.h>

#define BB 16
#define QQ 500
#define NN 128
#define KK2 34   // 17 keypoints * 2

// ---------------------------------------------------------------------------
// Kernel 1: cost matrix  C[b][q][n]  (fp32, exact op order of the reference)
// Also writes transposed CT[b][n][q]. UNCHANGED (numerics must stay identical).
// ---------------------------------------------------------------------------
__global__ __launch_bounds__(128) void cost_kernel(
    const float* __restrict__ pb,   // (B,Q,4) cxcywh
    const float* __restrict__ pk,   // (B,Q,17,2)
    const float* __restrict__ tb,   // (B,N,4)
    const float* __restrict__ tk,   // (B,N,17,2)
    float* __restrict__ C,          // (B,Q,N)
    float* __restrict__ CT,         // (B,N,Q) or nullptr
    int writeCT)
{
#pragma clang fp contract(off)
    const int q = blockIdx.x;
    const int b = blockIdx.y;
    const int n = threadIdx.x;

    __shared__ float spb[4];
    __shared__ float spk[KK2];
    if (threadIdx.x < 4)
        spb[threadIdx.x] = pb[((size_t)b * QQ + q) * 4 + threadIdx.x];
    if (threadIdx.x < KK2)
        spk[threadIdx.x] = pk[((size_t)b * QQ + q) * KK2 + threadIdx.x];
    __syncthreads();

    const float pcx = spb[0], pcy = spb[1], pw = spb[2], ph = spb[3];

    const size_t tbase = ((size_t)b * NN + n) * 4;
    const float tcx = tb[tbase + 0];
    const float tcy = tb[tbase + 1];
    const float tw  = tb[tbase + 2];
    const float th  = tb[tbase + 3];

    float cb = fabsf(pcx - tcx);
    cb = cb + fabsf(pcy - tcy);
    cb = cb + fabsf(pw - tw);
    cb = cb + fabsf(ph - th);

    float px0 = pcx - 0.5f * pw;
    float py0 = pcy - 0.5f * ph;
    float px1 = pcx + 0.5f * pw;
    float py1 = pcy + 0.5f * ph;
    px1 = fmaxf(px1, px0 + 1e-4f);
    py1 = fmaxf(py1, py0 + 1e-4f);

    float tx0 = tcx - 0.5f * tw;
    float ty0 = tcy - 0.5f * th;
    float tx1 = tcx + 0.5f * tw;
    float ty1 = tcy + 0.5f * th;
    tx1 = fmaxf(tx1, tx0 + 1e-4f);
    ty1 = fmaxf(ty1, ty0 + 1e-4f);

    const float area_p = (px1 - px0) * (py1 - py0);
    const float area_t = (tx1 - tx0) * (ty1 - ty0);

    const float ltx = fmaxf(px0, tx0);
    const float lty = fmaxf(py0, ty0);
    const float rbx = fminf(px1, tx1);
    const float rby = fminf(py1, ty1);
    const float wx = fmaxf(rbx - ltx, 0.0f);
    const float wy = fmaxf(rby - lty, 0.0f);
    const float inter = wx * wy;
    const float uni = (area_p + area_t) - inter;
    const float iou = inter / uni;

    const float ex0 = fminf(px0, tx0);
    const float ey0 = fminf(py0, ty0);
    const float ex1 = fmaxf(px1, tx1);
    const float ey1 = fmaxf(py1, ty1);
    const float ewx = fmaxf(ex1 - ex0, 0.0f);
    const float ewy = fmaxf(ey1 - ey0, 0.0f);
    const float enc = ewx * ewy;

    const float giou = iou - (enc - uni) / enc;
    const float cg = -giou;

    const size_t kbase = ((size_t)b * NN + n) * KK2;
    float ck = 0.0f;
    for (int k = 0; k < KK2; ++k)
        ck = ck + fabsf(spk[k] - tk[kbase + k]);

    const float Cv = (5.0f * cb + 2.0f * cg) + ck;

    C[((size_t)b * QQ + q) * NN + n] = Cv;
    if (writeCT)
        CT[((size_t)b * NN + n) * QQ + q] = Cv;
}

// uniform-lane readlane helpers (scalar pipe, no LDS)
__device__ __forceinline__ int rl_i(int v, int l) {
    return __builtin_amdgcn_readlane(v, l);
}
__device__ __forceinline__ double rl_d(double v, int l) {
    int lo = __builtin_amdgcn_readlane(__double2loint(v), l);
    int hi = __builtin_amdgcn_readlane(__double2hiint(v), l);
    return __hiloint2double(hi, lo);
}

// one DPP min step on f64 (two 32-bit dpp movs + v_min_f64)
template <int CTRL>
__device__ __forceinline__ double dpp_fmin_step(double x) {
    int lo = __double2loint(x);
    int hi = __double2hiint(x);
    int nlo = __builtin_amdgcn_update_dpp(lo, lo, CTRL, 0xF, 0xF, false);
    int nhi = __builtin_amdgcn_update_dpp(hi, hi, CTRL, 0xF, 0xF, false);
    return fmin(__hiloint2double(nhi, nlo), x);
}
#define ROW_SHR1  0x111
#define ROW_SHR2  0x112
#define ROW_SHR4  0x114
#define ROW_SHR8  0x118
#define ROW_BC15  0x142
#define ROW_BC31  0x143

__device__ __forceinline__ double dpp_fmin_wave(double x) {
    x = dpp_fmin_step<ROW_SHR1>(x);
    x = dpp_fmin_step<ROW_SHR2>(x);
    x = dpp_fmin_step<ROW_SHR4>(x);
    x = dpp_fmin_step<ROW_SHR8>(x);
    x = dpp_fmin_step<ROW_BC15>(x);
    x = dpp_fmin_step<ROW_BC31>(x);
    return x;   // lane 63 holds the wave min
}

// constant-index select/scatter on 8-arrays (register-resident, rule #20)
#define SEL8(arr, kq, out) do { \
    out = arr[0]; \
    if ((kq)==1) out = arr[1]; if ((kq)==2) out = arr[2]; if ((kq)==3) out = arr[3]; \
    if ((kq)==4) out = arr[4]; if ((kq)==5) out = arr[5]; if ((kq)==6) out = arr[6]; \
    if ((kq)==7) out = arr[7]; } while (0)

#define SCAT8(arr, kq, val) do { \
    if ((kq)==0) arr[0] = (val); if ((kq)==1) arr[1] = (val); \
    if ((kq)==2) arr[2] = (val); if ((kq)==3) arr[3] = (val); \
    if ((kq)==4) arr[4] = (val); if ((kq)==5) arr[5] = (val); \
    if ((kq)==6) arr[6] = (val); if ((kq)==7) arr[7] = (val); } while (0)

// ---------------------------------------------------------------------------
// Kernel 1.5: per-row min + first-occurrence argmin of CT rows.
// One block (64 lanes) per (row, batch). Packs exact f64(min)|9-bit-index
// (f32->f64 leaves 29 zero mantissa bits; mask recovers u exactly).
// ---------------------------------------------------------------------------
__global__ __launch_bounds__(64) void rowmin_kernel(
    const float* __restrict__ CT,   // (B,N,Q)
    double* __restrict__ rm)        // (B,N) packed f64(min)|argmin
{
    const int n = blockIdx.x;
    const int b = blockIdx.y;
    const int lane = threadIdx.x;

    const float4* r4 = reinterpret_cast<const float4*>(CT + ((size_t)b * NN + n) * QQ);

    float m = INFINITY;
    int jm = 0;
    {
        float4 a = r4[lane];             // elements 4*lane .. 4*lane+3
        int base = lane * 4;
        if (a.x < m) { m = a.x; jm = base + 0; }
        if (a.y < m) { m = a.y; jm = base + 1; }
        if (a.z < m) { m = a.z; jm = base + 2; }
        if (a.w < m) { m = a.w; jm = base + 3; }
    }
    if (lane < 61) {                     // 500/4 = 125 float4s total
        float4 a = r4[64 + lane];
        int base = (64 + lane) * 4;
        if (a.x < m) { m = a.x; jm = base + 0; }
        if (a.y < m) { m = a.y; jm = base + 1; }
        if (a.z < m) { m = a.z; jm = base + 2; }
        if (a.w < m) { m = a.w; jm = base + 3; }
    }

    long long kb = __double_as_longlong((double)m) | (long long)jm;
    double kd = dpp_fmin_wave(__longlong_as_double(kb));
    if (lane == 63)
        rm[(size_t)b * NN + n] = kd;
}

// ---------------------------------------------------------------------------
// Kernel 2: per-batch rectangular LSA (JV / shortest augmenting path) on
// cost[b].T (N=128 rows x Q=500 cols). Row reduction + greedy init, then
// LAPJV augmenting-row-reduction (ARR), then SAP for leftover rows.
// Invariants maintained at every step: rc = C-u-v >= 0; matched edges tight;
// v <= 0 and every v<0 column is matched (rectangular-LP dual feasibility).
// -> final matching is the exact optimum == reference (unique optimum).
// ONE WAVE per batch. Lane l owns columns j = 8l..8l+7 and rows l, l+64.
// ---------------------------------------------------------------------------
template <bool USE_CT, bool PRE>
__global__ __launch_bounds__(64) void lsa_wave_kernel(
    const float* __restrict__ C,    // (B,Q,N)
    const float* __restrict__ CT,   // (B,N,Q) or nullptr
    const double* __restrict__ rm,  // (B,N) packed rowmin or nullptr
    float* __restrict__ out_rows,   // (B,N) as float
    float* __restrict__ out_cols)   // (B,N) as float
{
#pragma clang fp contract(off)
    const int b = blockIdx.x;
    const int lane = threadIdx.x;

    __shared__ double s_spc[64 * 10];   // stride 10 doubles (80 B) per lane
    __shared__ int s_q[NN];

    const float* Cb  = C + (size_t)b * QQ * NN;
    const float* CTb = USE_CT ? (CT + (size_t)b * NN * QQ) : nullptr;

    const int j0 = lane * 8;
    const int nval = (QQ - j0 < 0) ? 0 : ((QQ - j0 > 8) ? 8 : (QQ - j0));

    double v_[8], spc_[8];
    int path_[8], r4c_[8];
    double u0, u1;
    int c4r0 = -1, c4r1 = -1;
    int jm0, jm1;
#pragma unroll
    for (int k = 0; k < 8; ++k) { v_[k] = 0.0; r4c_[k] = -1; }

    // ---- Phase A: row minima (u) from rowmin kernel + L2 warm pass ----
    if (PRE) {
        const long long p0 = __double_as_longlong(rm[(size_t)b * NN + lane]);
        const long long p1 = __double_as_longlong(rm[(size_t)b * NN + 64 + lane]);
        u0 = __longlong_as_double(p0 & ~0x1FFLL);
        u1 = __longlong_as_double(p1 & ~0x1FFLL);
        jm0 = (int)(p0 & 0x1FF);
        jm1 = (int)(p1 & 0x1FF);
        if (USE_CT) {
            // coalesced warm pass: pull this batch's CT slice into local L2
            const float4* w4 = reinterpret_cast<const float4*>(CTb);
            float4 acc; acc.x = acc.y = acc.z = acc.w = 0.0f;
#pragma unroll 8
            for (int t = lane; t < (NN * QQ) / 4; t += 64) {
                float4 a = w4[t];
                acc.x += a.x; acc.y += a.y; acc.z += a.z; acc.w += a.w;
            }
            asm volatile("" :: "v"(acc.x), "v"(acc.y), "v"(acc.z), "v"(acc.w));
        }
    } else {
        float m0 = INFINITY, m1 = INFINITY;
        jm0 = 0; jm1 = 0;
#pragma unroll 4
        for (int q = 0; q < QQ; ++q) {
            float a, c;
            if (USE_CT) {
                a = CTb[(size_t)lane * QQ + q];
                c = CTb[(size_t)(64 + lane) * QQ + q];
            } else {
                a = Cb[(size_t)q * NN + lane];
                c = Cb[(size_t)q * NN + 64 + lane];
            }
            if (a < m0) { m0 = a; jm0 = q; }
            if (c < m1) { m1 = c; jm1 = q; }
        }
        u0 = (double)m0;
        u1 = (double)m1;
    }

    // ---- Phase B: greedy matching on row minima (sequential, uniform) ----
    for (int i = 0; i < NN; ++i) {
        int jm = (i < 64) ? rl_i(jm0, i) : rl_i(jm1, i - 64);
        int kq = jm & 7;
        int selr; SEL8(r4c_, kq, selr);
        int occ = rl_i(selr, jm >> 3);
        if (occ < 0) {
            if (lane == (jm >> 3)) { SCAT8(r4c_, kq, i); }
            if (i < 64) { if (lane == i) c4r0 = jm; }
            else        { if (lane == i - 64) c4r1 = jm; }
        }
    }

    // ---- Phase B2: augmenting row reduction (LAPJV ARR) ----
    // For each free row: (m1,j1,m2) over t_j = C(i,j) - v_j.
    // m1<m2: u[i]=m2, v[j1]-=(m2-m1) (v only DECREASES -> rectangular-valid),
    // take j1 (displaced owner continues the chain). m1==m2 & j1 taken: leave
    // for SAP with refreshed u[i]=m1 (still feasible). Step cap -> SAP fallback.
    if (USE_CT) {
        unsigned long long fr0 = __ballot(c4r0 < 0);
        unsigned long long fr1 = __ballot(c4r1 < 0);
        int steps = 0;
        int i = -1;
        while (steps < 192) {
            if (i < 0) {
                if (fr0)      { i = __ffsll((long long)fr0) - 1; fr0 &= fr0 - 1; }
                else if (fr1) { i = 64 + (__ffsll((long long)fr1) - 1); fr1 &= fr1 - 1; }
                else break;
            }
            ++steps;
            // row i, my 8 columns (coalesced float4 from CT; L2-warm)
            float c_[8];
            {
                const float4* p = reinterpret_cast<const float4*>(CTb + (size_t)i * QQ + j0);
                if (nval > 0) { float4 a = p[0]; c_[0]=a.x; c_[1]=a.y; c_[2]=a.z; c_[3]=a.w; }
                else { c_[0]=c_[1]=c_[2]=c_[3]=0.0f; }
                if (nval > 4) { float4 a = p[1]; c_[4]=a.x; c_[5]=a.y; c_[6]=a.z; c_[7]=a.w; }
                else { c_[4]=c_[5]=c_[6]=c_[7]=0.0f; }
            }
            // lane-local two smallest of t (exact f64) + local argmin
            double m1 = INFINITY, m2 = INFINITY; int jl = 0;
#pragma unroll
            for (int k = 0; k < 8; ++k) {
                double t = (k < nval) ? ((double)c_[k] - v_[k]) : INFINITY;
                bool lt1 = t < m1;
                m2 = lt1 ? m1 : fmin(m2, t);
                jl = lt1 ? (j0 + k) : jl;
                m1 = lt1 ? t : m1;
            }
            // exact wave min1 + first-occurrence winner (ballot, no packing)
            double g1 = rl_d(dpp_fmin_wave(m1), 63);
            unsigned long long bl = __ballot(m1 == g1);
            int winner = __ffsll((long long)bl) - 1;
            int j1 = rl_i(jl, winner);
            // wave min2 = min( m2[winner], m1[lane != winner] )
            double a2 = (lane == winner) ? m2 : m1;
            double g2 = rl_d(dpp_fmin_wave(a2), 63);
            // owner of column j1
            int kq = j1 & 7;
            int selr; SEL8(r4c_, kq, selr);
            int i0 = rl_i(selr, j1 >> 3);

            if (g1 < g2) {
                // u[i]=g2; v[j1]-=(g2-g1); match i->j1 (tight: rc=0 exactly)
                if (i < 64) { if (lane == i) { u0 = g2; c4r0 = j1; } }
                else        { if (lane == i - 64) { u1 = g2; c4r1 = j1; } }
                if (lane == (j1 >> 3)) {
                    double vv; SEL8(v_, kq, vv);
                    vv = vv - (g2 - g1);
                    SCAT8(v_, kq, vv);
                    SCAT8(r4c_, kq, i);
                }
                if (i0 >= 0) {
                    if (i0 < 64) { if (lane == i0) c4r0 = -1; }
                    else         { if (lane == i0 - 64) c4r1 = -1; }
                    i = i0;        // displaced row continues the chain
                } else {
                    i = -1;        // matched a free column; next free row
                }
            } else {
                if (i0 < 0) {
                    // exact tie but j1 free: u[i]=g1, match (tight, no v change)
                    if (i < 64) { if (lane == i) { u0 = g1; c4r0 = j1; } }
                    else        { if (lane == i - 64) { u1 = g1; c4r1 = j1; } }
                    if (lane == (j1 >> 3)) { SCAT8(r4c_, kq, i); }
                } else {
                    // leave row free for SAP; refresh u[i]=g1 (rc >= 0 kept)
                    if (i < 64) { if (lane == i) u0 = g1; }
                    else        { if (lane == i - 64) u1 = g1; }
                }
                i = -1;
            }
        }
    }

    // ---- Phase C: shortest augmenting path for remaining free rows ----
    // (round-6-validated packed-spc implementation, verbatim)
    for (int cur = 0; cur < NN; ++cur) {
        int already = (cur < 64) ? rl_i(c4r0, cur) : rl_i(c4r1, cur - 64);
        if (already >= 0) continue;

        const double INF = INFINITY;
#pragma unroll
        for (int k = 0; k < 8; ++k) { spc_[k] = INF; path_[k] = -1; }
        unsigned int sc = 0;
        int sr0 = 0, sr1 = 0;
        double minv = 0.0;
        int i = cur, sink = -1;

        while (true) {
            // ---- cost row i, my 8 columns (coalesced float4 from CT) ----
            float c_[8];
            if (USE_CT) {
                const float4* p = reinterpret_cast<const float4*>(CTb + (size_t)i * QQ + j0);
                if (nval > 0) {
                    float4 a = p[0];
                    c_[0] = a.x; c_[1] = a.y; c_[2] = a.z; c_[3] = a.w;
                } else { c_[0] = c_[1] = c_[2] = c_[3] = 0.0f; }
                if (nval > 4) {
                    float4 a = p[1];
                    c_[4] = a.x; c_[5] = a.y; c_[6] = a.z; c_[7] = a.w;
                } else { c_[4] = c_[5] = c_[6] = c_[7] = 0.0f; }
            } else {
#pragma unroll
                for (int k = 0; k < 8; ++k)
                    c_[k] = (j0 + k < QQ) ? Cb[(size_t)(j0 + k) * NN + i] : 0.0f;
            }

            // SR[i] = True
            if (i < 64) { if (lane == i) sr0 = 1; }
            else        { if (lane == i - 64) sr1 = 1; }

            // u[i] broadcast — uniform i => readlane
            double ui = (i < 64) ? rl_d(u0, i) : rl_d(u1, i - 64);
            double s = minv - ui;   // wave-uniform

            // relax + pack column index into low mantissa bits
#pragma unroll
            for (int k = 0; k < 8; ++k) {
                double r = (s + (double)c_[k]) - v_[k];
                long long rb = (__double_as_longlong(r) & ~0x1FFLL)
                             | (long long)(j0 + k);
                double rp = __longlong_as_double(rb);
                bool ok = (k < nval) && !((sc >> k) & 1) && (rp < spc_[k]);
                if (ok) { spc_[k] = rp; path_[k] = i; }
            }

            // local min: mask (SC/invalid -> inf) + pure fmin tree (no idx sel)
            double val[8];
#pragma unroll
            for (int k = 0; k < 8; ++k) {
                bool okk = (k < nval) && !((sc >> k) & 1);
                val[k] = okk ? spc_[k] : INF;
            }
            double t01 = fmin(val[0], val[1]);
            double t23 = fmin(val[2], val[3]);
            double t45 = fmin(val[4], val[5]);
            double t67 = fmin(val[6], val[7]);
            double lmin = fmin(fmin(t01, t23), fmin(t45, t67));

            // wave min via DPP chain; lane 63 holds global packed min
            double gk = rl_d(dpp_fmin_wave(lmin), 63);

            int jmin   = (int)(__double_as_longlong(gk) & 0x1FFLL);
            int winner = jmin >> 3;

            // SC[jmin] = True
            if (lane == winner) sc |= 1u << (jmin & 7);

            // r4 = row4col[jmin]  (uniform => readlane)
            int kq = jmin & 7;
            int selr; SEL8(r4c_, kq, selr);
            int r4 = rl_i(selr, winner);

            minv = gk;              // == spc[jmin] exactly (packed)
            if (r4 < 0) { sink = jmin; break; }
            i = r4;
        }

        // ---- spill spc to LDS for the col4row gather ----
        {
            double* base = s_spc + lane * 10;
            double2 d01; d01.x = spc_[0]; d01.y = spc_[1];
            double2 d23; d23.x = spc_[2]; d23.y = spc_[3];
            double2 d45; d45.x = spc_[4]; d45.y = spc_[5];
            double2 d67; d67.x = spc_[6]; d67.y = spc_[7];
            *(double2*)(base + 0) = d01;
            *(double2*)(base + 2) = d23;
            *(double2*)(base + 4) = d45;
            *(double2*)(base + 6) = d67;
        }
        __syncthreads();
        const int g0i = (c4r0 < 0) ? 0 : c4r0;
        const int g1i = (c4r1 < 0) ? 0 : c4r1;
        const double g0 = s_spc[(g0i >> 3) * 10 + (g0i & 7)];
        const double g1 = s_spc[(g1i >> 3) * 10 + (g1i & 7)];

        // ---- dual updates (pre-augmentation col4row) ----
        if (lane == cur) { u0 = u0 + minv; }
        else if (sr0)    { double t = minv - g0; u0 = u0 + t; }
        if (lane + 64 == cur) { u1 = u1 + minv; }
        else if (sr1)         { double t = minv - g1; u1 = u1 + t; }
#pragma unroll
        for (int k = 0; k < 8; ++k) {
            if ((k < nval) && ((sc >> k) & 1)) {
                double t = minv - spc_[k];
                v_[k] = v_[k] - t;
            }
        }
        __syncthreads();   // spc LDS region reused next augmentation

        // ---- augment along alternating path (uniform j walk, readlane) ----
        int j = sink;
        while (true) {
            int kq = j & 7, src = j >> 3;
            int sp; SEL8(path_, kq, sp);
            int i2 = rl_i(sp, src);
            if (lane == src) { SCAT8(r4c_, kq, i2); }   // row4col[j] = i2
            int t2;
            if (i2 < 64) {
                t2 = rl_i(c4r0, i2);
                if (lane == i2) c4r0 = j;
            } else {
                t2 = rl_i(c4r1, i2 - 64);
                if (lane == i2 - 64) c4r1 = j;
            }
            j = t2;
            if (i2 == cur) break;
        }
    }

    // ---- output: rows = sorted assigned-query idx, cols = target idx ----
    s_q[lane] = c4r0;
    s_q[64 + lane] = c4r1;
    __syncthreads();
    int rank0 = 0, rank1 = 0;
    for (int t = 0; t < NN; ++t) {
        int qv = s_q[t];
        rank0 += (qv < c4r0) ? 1 : 0;
        rank1 += (qv < c4r1) ? 1 : 0;
    }
    out_rows[(size_t)b * NN + rank0] = (float)c4r0;
    out_cols[(size_t)b * NN + rank0] = (float)lane;
    out_rows[(size_t)b * NN + rank1] = (float)c4r1;
    out_cols[(size_t)b * NN + rank1] = (float)(64 + lane);
}

// ---------------------------------------------------------------------------
extern "C" void kernel_launch(void* const* d_in, const int* in_sizes, int n_in,
                              void* d_out, int out_size, void* d_ws, size_t ws_size,
                              hipStream_t stream) {
    const float* pb = (const float*)d_in[0];  // pred_boxes     (B,Q,4)
    const float* pk = (const float*)d_in[1];  // pred_keypoints (B,Q,17,2)
    const float* tb = (const float*)d_in[2];  // tgt_boxes      (B,N,4)
    const float* tk = (const float*)d_in[3];  // tgt_keypoints  (B,N,17,2)

    float* outC  = (float*)d_out;                      // (B,Q,N)
    float* orows = outC + (size_t)BB * QQ * NN;        // (B,N)
    float* ocols = orows + (size_t)BB * NN;            // (B,N)

    const size_t ct_bytes = (size_t)BB * NN * QQ * sizeof(float);  // 4,096,000
    const size_t rm_bytes = (size_t)BB * NN * sizeof(double);      //    16,384
    const bool useCT = (ws_size >= ct_bytes);
    const bool pre   = (ws_size >= ct_bytes + rm_bytes);
    float*  CT = useCT ? (float*)d_ws : nullptr;
    double* RM = pre ? (double*)((char*)d_ws + ct_bytes) : nullptr;

    dim3 grid(QQ, BB);
    cost_kernel<<<grid, 128, 0, stream>>>(pb, pk, tb, tk, outC, CT, useCT ? 1 : 0);

    if (pre) {
        rowmin_kernel<<<dim3(NN, BB), 64, 0, stream>>>(CT, RM);
        lsa_wave_kernel<true, true><<<BB, 64, 0, stream>>>(outC, CT, RM, orows, ocols);
    } else if (useCT) {
        lsa_wave_kernel<true, false><<<BB, 64, 0, stream>>>(outC, CT, nullptr, orows, ocols);
    } else {
        lsa_wave_kernel<false, false><<<BB, 64, 0, stream>>>(outC, nullptr, nullptr, orows, ocols);
    }
}